// Round 12
// baseline (602.081 us; speedup 1.0000x reference)
//
#include <hip/hip_runtime.h>
#include <math.h>
#include <cmath>

#define SEQ   512
#define NBATCH 64
#define BT    32768      // 64*512 tokens
#define HID   128
#define NHEAD 4
#define HD    32
#define VHD   64
#define VDIM  256
#define FFND  256

typedef __attribute__((ext_vector_type(8))) short bf16x8;
typedef __attribute__((ext_vector_type(4))) float f32x4;
typedef unsigned short u16;

__device__ __forceinline__ float gelu_f(float x){ return 0.5f*x*(1.f+erff(x*0.70710678118f)); }

// HW bf16 convert (compiler-native __bf16 cast; RTNE)
__device__ __forceinline__ u16 f2bf(float f){
  __bf16 h = (__bf16)f;
  union{__bf16 h; u16 u;} v; v.h = h; return v.u;
}
__device__ __forceinline__ float bf2f(u16 u){
  union{unsigned u; float f;} v; v.u = ((unsigned)u)<<16; return v.f;
}

// async 16B global->LDS (HW scatters lane i at ldsbase + i*16)
__device__ __forceinline__ void gload16(const void* g, void* l){
  __builtin_amdgcn_global_load_lds(
      (const __attribute__((address_space(1))) unsigned*)g,
      (__attribute__((address_space(3))) unsigned*)l, 16, 0, 0);
}

// stage a 128-row x 128-u16 weight tile, XOR-swizzled (phys16 = log16 ^ (row&15))
// B-frag read: logical (row, ks*32+quad*8) -> sW[row*128 + (((ks*4+quad)^(row&15))<<3)]
#define STAGE_TILE_N(dst, base, strideU16, colOffU16, wid_, srow_, phys16l_, NIT) \
  do{                                                                           \
    _Pragma("unroll")                                                           \
    for(int it_=0; it_<NIT; it_++){                                             \
      int blk_ = (wid_)*NIT + it_;                                              \
      int row_ = blk_*4 + (srow_);                                              \
      int log16_ = (phys16l_) ^ (row_&15);                                      \
      gload16((base) + (size_t)row_*(strideU16) + (colOffU16) + log16_*8,       \
              &(dst)[blk_*512]);                                                \
    }                                                                           \
  }while(0)

#define STAGE_TILE(dst, base, strideU16, colOffU16, wid_, srow_, phys16l_) \
  STAGE_TILE_N(dst, base, strideU16, colOffU16, wid_, srow_, phys16l_, 8)

// ---------------- weight convert + transpose -> bf16 Wt[N][K] ----------------
// per-layer region (196608 u16): [0)qkvg 768x128  [98304)wo 128x256  [131072)f1 256x128  [163840)f2 128x256
// tail: 786432 dec_w1t 64x128 (8192); 794624 rem_w2t 64x32 (2048); 796672 rem_w3t 128x64 (8192). total 804864
__global__ __launch_bounds__(256) void wconv_kernel(
    const float* __restrict__ wq, const float* __restrict__ wk,
    const float* __restrict__ wv, const float* __restrict__ wg,
    const float* __restrict__ wo, const float* __restrict__ f1,
    const float* __restrict__ f2, const float* __restrict__ dw1,
    const float* __restrict__ w2e, const float* __restrict__ w3e,
    u16* __restrict__ Wt)
{
  int idx = blockIdx.x*256 + threadIdx.x;   // 0..804863
  if(idx >= 786432){
    int q = idx - 786432;
    if(q < 8192){ int col=q>>7, h=q&127; Wt[idx]=f2bf(dw1[h*64+col]); }
    else if(q < 10240){ int p=q-8192; int row=p>>5, col=p&31; Wt[idx]=f2bf(w2e[col*64+row]); }
    else { int p=q-10240; int row=p>>6, col=p&63; Wt[idx]=f2bf(w3e[col*128+row]); }
    return;
  }
  int layer = idx / 196608;
  int r = idx - layer*196608;
  u16* W = Wt + (size_t)layer*196608;
  const float* wq_l = wq + (size_t)layer*16384;
  const float* wk_l = wk + (size_t)layer*16384;
  const float* wv_l = wv + (size_t)layer*32768;
  const float* wg_l = wg + (size_t)layer*32768;
  const float* wo_l = wo + (size_t)layer*32768;
  const float* f1_l = f1 + (size_t)layer*32768;
  const float* f2_l = f2 + (size_t)layer*32768;
  float v;
  if(r < 98304){
    int col = r>>7, h = r&127;
    if(col<128){ int n=col>>5, d=col&31; v = wq_l[(n*128+h)*32+d]; }
    else if(col<256){ int c=col-128, n=c>>5, d=c&31; v = wk_l[(n*128+h)*32+d]; }
    else if(col<512){ int c=col-256, n=c>>6, j=c&63; v = wv_l[(n*128+h)*64+j]; }
    else { int p=col-512; v = wg_l[h*256+p]; }
    W[r] = f2bf(v);
  } else if(r < 131072){
    int q = r-98304; int col=q>>8, k=q&255;
    W[r] = f2bf(wo_l[k*128+col]);
  } else if(r < 163840){
    int q = r-131072; int col=q>>7, h=q&127;
    W[r] = f2bf(f1_l[h*256+col]);
  } else {
    int q = r-163840; int col=q>>8, k=q&255;
    W[r] = f2bf(f2_l[k*128+col]);
  }
}

// ---------------- qkvg epilogue helper (4-wave version, used by embed_kernel) ----------------
__device__ __forceinline__ void qkvg_epilogue(
    int nc, f32x4 acc[2][4], u16* stg,
    int t, int mrow, int quad, int r0q, int c0q, int b, int l0, int tok0,
    u16* __restrict__ Q, u16* __restrict__ K,
    u16* __restrict__ Vt, u16* __restrict__ G)
{
  if(nc < 2){
    bool isK = (nc==1);
    float sgn = isK ? -1.f : 1.f;
    #pragma unroll
    for(int cc=0;cc<4;cc++){
      int colc = c0q + cc*16 + mrow;
      int i = (colc&31)>>1;
      float log2bs = log2f(((float)i + 12.8f)*(1.f/44.8f));
      float invf   = exp2f(-(float)i * (13.28771238f/16.f));
      float rstep  = exp2f(sgn*log2bs*(1.f/512.f));
      float c1 = cosf(invf), s1 = sinf(invf);
      #pragma unroll
      for(int rr=0;rr<2;rr++){
        int rowl0 = r0q + rr*16 + quad*4;
        float lb = (float)(l0 + rowl0);
        float sc = exp2f(sgn*log2bs*lb*(1.f/512.f));
        float ang = lb*invf;
        float u = cosf(ang)*sc, v = sinf(ang)*sc;
        #pragma unroll
        for(int reg=0;reg<4;reg++){
          int rowl = rowl0 + reg;
          float val = acc[rr][cc][reg];
          float partner = __shfl_xor(val, 1);
          float o = (colc&1) ? (val*u + partner*v) : (val*u - partner*v);
          stg[rowl*136 + colc] = f2bf(o);
          float un = (u*c1 - v*s1)*rstep;
          float vn = (u*s1 + v*c1)*rstep;
          u = un; v = vn;
        }
      }
    }
    __syncthreads();
    u16* O = isK ? K : Q;
    for(int th=t; th<1024; th+=256){
      int row=th>>4, n=(th>>2)&3, seg=th&3;
      *(uint4*)&O[(((size_t)(b*4+n)*512) + (l0+row))*32 + seg*8]
        = *(const uint4*)&stg[row*136 + n*32 + seg*8];
    }
  } else if(nc < 4){
    #pragma unroll
    for(int cc=0;cc<4;cc++){
      int colc = c0q + cc*16 + mrow;
      #pragma unroll
      for(int rr=0;rr<2;rr++){
        #pragma unroll
        for(int reg=0;reg<4;reg++){
          int rowl = r0q + rr*16 + quad*4 + reg;
          stg[colc*72 + rowl] = f2bf(acc[rr][cc][reg]);
        }
      }
    }
    __syncthreads();
    int jbase = (nc-2)*128;
    for(int th=t; th<1024; th+=256){
      int row=th>>3, seg=th&7;
      int jg = jbase + row; int n = jg>>6, j = jg&63;
      *(uint4*)&Vt[(((size_t)(b*4+n)*64) + j)*512 + l0 + seg*8]
        = *(const uint4*)&stg[row*72 + seg*8];
    }
  } else {
    #pragma unroll
    for(int cc=0;cc<4;cc++){
      int colc = c0q + cc*16 + mrow;
      #pragma unroll
      for(int rr=0;rr<2;rr++){
        #pragma unroll
        for(int reg=0;reg<4;reg++){
          int rowl = r0q + rr*16 + quad*4 + reg;
          stg[rowl*136 + colc] = f2bf(acc[rr][cc][reg]);
        }
      }
    }
    __syncthreads();
    int gc0 = (nc-4)*128;
    for(int th=t; th<1024; th+=256){
      int row=th>>4, seg=th&15;
      *(uint4*)&G[((size_t)(tok0+row))*256 + gc0 + seg*8]
        = *(const uint4*)&stg[row*136 + seg*8];
    }
  }
}

// ---------------- embed (MFMA) + layer-0 LN1 + FUSED layer-0 qkvg ----------------
// xn never leaves LDS: big[0..8704) holds xn (stride 136); weight chunks stage into
// big[8704..25088); epilogue staging tops out at 8704+9216=17920. All disjoint.
__global__ __launch_bounds__(256) void embed_kernel(
    const float* __restrict__ x,
    const float* __restrict__ w1, const float* __restrict__ b1,
    const float* __restrict__ b2, const float* __restrict__ b3,
    const u16* __restrict__ W23t,     // w2t[64][32] at 0, w3t[128][64] at 2048
    const float* __restrict__ lnw, const float* __restrict__ lnb,
    const u16* __restrict__ Wt,       // layer-0 qkvg weights (6 x 16384)
    float* __restrict__ X,
    u16* __restrict__ Q, u16* __restrict__ K,
    u16* __restrict__ Vt, u16* __restrict__ G)
{
  __shared__ float sx[64][6];
  __shared__ float sw1[160], sb1[32], sb2[64], sb3[128];
  __shared__ u16 big[25088];
  int t=threadIdx.x, lane=t&63, wid=t>>6, mrow=lane&15, quad=lane>>4, r0=wid*16;
  int tok0=blockIdx.x*64;

  for(int i=t;i<320;i+=256) sx[i/5][i%5]=x[(size_t)tok0*5+i];
  for(int i=t;i<160;i+=256) sw1[i]=w1[i];
  if(t<32) sb1[t]=b1[t];
  if(t<64) sb2[t]=b2[t];
  if(t<128) sb3[t]=b3[t];
  for(int c=t;c<256;c+=256){ int row=c>>2, c8=(c&3)*8;
    *(uint4*)&big[2560+row*40+c8]=*(const uint4*)&W23t[row*32+c8]; }
  for(int c=t;c<1024;c+=256){ int row=c>>3, c8=(c&7)*8;
    *(uint4*)&big[9728+row*72+c8]=*(const uint4*)&W23t[2048+row*64+c8]; }
  __syncthreads();

  for(int task=t; task<2048; task+=256){
    int tok=task>>5, j=task&31;
    float a=sb1[j];
    #pragma unroll
    for(int i=0;i<5;i++) a+=sx[tok][i]*sw1[i*32+j];
    big[tok*40+j]=f2bf(gelu_f(a));
  }
  __syncthreads();

  f32x4 h2[4];
  #pragma unroll
  for(int cc=0;cc<4;cc++) h2[cc]=(f32x4){0.f,0.f,0.f,0.f};
  {
    bf16x8 a=*(const bf16x8*)&big[(r0+mrow)*40+quad*8];
    #pragma unroll
    for(int cc=0;cc<4;cc++){
      bf16x8 b=*(const bf16x8*)&big[2560+(cc*16+mrow)*40+quad*8];
      h2[cc]=__builtin_amdgcn_mfma_f32_16x16x32_bf16(a,b,h2[cc],0,0,0);
    }
  }
  #pragma unroll
  for(int cc=0;cc<4;cc++){
    float bs=sb2[cc*16+mrow];
    #pragma unroll
    for(int reg=0;reg<4;reg++)
      big[5120+(r0+quad*4+reg)*72+cc*16+mrow]=f2bf(gelu_f(h2[cc][reg]+bs));
  }
  __syncthreads();

  f32x4 xac[8];
  #pragma unroll
  for(int cc=0;cc<8;cc++) xac[cc]=(f32x4){0.f,0.f,0.f,0.f};
  #pragma unroll
  for(int ks=0;ks<2;ks++){
    bf16x8 a=*(const bf16x8*)&big[5120+(r0+mrow)*72+ks*32+quad*8];
    #pragma unroll
    for(int cc=0;cc<8;cc++){
      bf16x8 b=*(const bf16x8*)&big[9728+(cc*16+mrow)*72+ks*32+quad*8];
      xac[cc]=__builtin_amdgcn_mfma_f32_16x16x32_bf16(a,b,xac[cc],0,0,0);
    }
  }
  __syncthreads();

  #pragma unroll
  for(int reg=0;reg<4;reg++){
    int rowl=r0+quad*4+reg, rowg=tok0+rowl;
    float xv[8], s=0.f, sq=0.f;
    #pragma unroll
    for(int cc=0;cc<8;cc++){
      float v=gelu_f(xac[cc][reg]+sb3[cc*16+mrow]);
      xv[cc]=v; s+=v; sq+=v*v;
    }
    #pragma unroll
    for(int m=1;m<16;m<<=1){ s+=__shfl_xor(s,m); sq+=__shfl_xor(sq,m); }
    float mu=s*(1.f/128.f);
    float var=sq*(1.f/128.f)-mu*mu;
    float rstd=rsqrtf(var+1e-5f);
    #pragma unroll
    for(int cc=0;cc<8;cc++){
      int col=cc*16+mrow;
      X[(size_t)rowg*128+col]=xv[cc];
      big[rowl*136+col]=f2bf((xv[cc]-mu)*rstd*lnw[col]+lnb[col]);
    }
  }
  __syncthreads();

  // ---- fused layer-0 qkvg: A-frags from xn in LDS; 6 chunks via big[8704..]
  u16* sW = big + 8704;
  u16* stg = sW;
  int srow = lane>>4, phys16l = lane&15;
  int r0q = (wid>>1)*32, c0q = (wid&1)*64;
  int b = tok0>>9, l0 = tok0&511;

  bf16x8 a0f[4], a1f[4];
  #pragma unroll
  for(int ks=0; ks<4; ks++){
    a0f[ks] = *(const bf16x8*)&big[(r0q+mrow)*136 + ks*32+quad*8];
    a1f[ks] = *(const bf16x8*)&big[(r0q+16+mrow)*136 + ks*32+quad*8];
  }
  __syncthreads();   // a-frag reads done (xn region stays intact anyway)

  for(int nc=0; nc<6; nc++){
    if(nc) __syncthreads();
    STAGE_TILE(sW, Wt + (size_t)nc*16384, 128, 0, wid, srow, phys16l);
    __syncthreads();

    f32x4 acc[2][4];
    #pragma unroll
    for(int rr=0;rr<2;rr++)
      #pragma unroll
      for(int cc=0;cc<4;cc++) acc[rr][cc] = (f32x4){0.f,0.f,0.f,0.f};
    #pragma unroll
    for(int ks=0; ks<4; ks++){
      #pragma unroll
      for(int cc=0; cc<4; cc++){
        bf16x8 bb = *(const bf16x8*)&sW[(c0q+cc*16+mrow)*128 + (((ks*4+quad)^mrow)<<3)];
        acc[0][cc] = __builtin_amdgcn_mfma_f32_16x16x32_bf16(a0f[ks],bb,acc[0][cc],0,0,0);
        acc[1][cc] = __builtin_amdgcn_mfma_f32_16x16x32_bf16(a1f[ks],bb,acc[1][cc],0,0,0);
      }
    }
    __syncthreads();
    qkvg_epilogue(nc, acc, stg, t, mrow, quad, r0q, c0q, b, l0, tok0, Q, K, Vt, G);
  }
}

// ---------------- qkvg epilogue helper (8-wave version, used by layer_kernel) ----------------
__device__ __forceinline__ void qkvg_epi8(
    int nc, f32x4 acc[4], u16* stg,
    int t, int mrow, int quad, int r0, int c0, int b, int l0, int tok0,
    u16* __restrict__ Q, u16* __restrict__ K,
    u16* __restrict__ Vt, u16* __restrict__ G)
{
  if(nc < 2){
    bool isK = (nc==1);
    float sgn = isK ? -1.f : 1.f;
    #pragma unroll
    for(int cc=0;cc<4;cc++){
      int colc = c0 + cc*16 + mrow;
      int i = (colc&31)>>1;
      float log2bs = log2f(((float)i + 12.8f)*(1.f/44.8f));
      float invf   = exp2f(-(float)i * (13.28771238f/16.f));
      float rstep  = exp2f(sgn*log2bs*(1.f/512.f));
      float c1 = cosf(invf), s1 = sinf(invf);
      int rowl0 = r0 + quad*4;
      float lb = (float)(l0 + rowl0);
      float sc = exp2f(sgn*log2bs*lb*(1.f/512.f));
      float ang = lb*invf;
      float u = cosf(ang)*sc, v = sinf(ang)*sc;
      #pragma unroll
      for(int reg=0;reg<4;reg++){
        int rowl = rowl0 + reg;
        float val = acc[cc][reg];
        float partner = __shfl_xor(val, 1);
        float o = (colc&1) ? (val*u + partner*v) : (val*u - partner*v);
        stg[rowl*136 + colc] = f2bf(o);
        float un = (u*c1 - v*s1)*rstep;
        float vn = (u*s1 + v*c1)*rstep;
        u = un; v = vn;
      }
    }
    __syncthreads();
    u16* O = isK ? K : Q;
    for(int th=t; th<1024; th+=512){
      int row=th>>4, n=(th>>2)&3, seg=th&3;
      *(uint4*)&O[(((size_t)(b*4+n)*512) + (l0+row))*32 + seg*8]
        = *(const uint4*)&stg[row*136 + n*32 + seg*8];
    }
  } else if(nc < 4){
    #pragma unroll
    for(int cc=0;cc<4;cc++){
      int colc = c0 + cc*16 + mrow;
      #pragma unroll
      for(int reg=0;reg<4;reg++){
        int rowl = r0 + quad*4 + reg;
        stg[colc*72 + rowl] = f2bf(acc[cc][reg]);
      }
    }
    __syncthreads();
    int jbase = (nc-2)*128;
    for(int th=t; th<1024; th+=512){
      int row=th>>3, seg=th&7;
      int jg = jbase + row; int n = jg>>6, j = jg&63;
      *(uint4*)&Vt[(((size_t)(b*4+n)*64) + j)*512 + l0 + seg*8]
        = *(const uint4*)&stg[row*72 + seg*8];
    }
  } else {
    #pragma unroll
    for(int cc=0;cc<4;cc++){
      int colc = c0 + cc*16 + mrow;
      #pragma unroll
      for(int reg=0;reg<4;reg++){
        int rowl = r0 + quad*4 + reg;
        stg[rowl*136 + colc] = f2bf(acc[cc][reg]);
      }
    }
    __syncthreads();
    int gc0 = (nc-4)*128;
    for(int th=t; th<1024; th+=512){
      int row=th>>4, seg=th&15;
      *(uint4*)&G[((size_t)(tok0+row))*256 + gc0 + seg*8]
        = *(const uint4*)&stg[row*136 + seg*8];
    }
  }
}

// ---------------- fused LAYER kernel: retention (4 heads) + MLP + qkvg(next) / dec(last) ----------------
// Ret LDS strides PADDED for bank-conflict-free access (round 12):
//   rK stride 44 u16 (bank(row)=row*22 mod 32: 16 distinct), rV/rS stride 76
//   (bank(row)=row*6 mod 32: 16 distinct). Per head 12544 u16; 2 heads = 25088 < 32768.
__global__ __launch_bounds__(512, 4) void layer_kernel(
    const u16* __restrict__ Qin, const u16* __restrict__ Kin,
    const u16* __restrict__ Vtin, const u16* __restrict__ Gin,
    const float* __restrict__ gnw, const float* __restrict__ gnb, float4 l2g,
    const u16* __restrict__ Wo,
    const u16* __restrict__ W1t, const float* __restrict__ b1,
    const u16* __restrict__ W2t, const float* __restrict__ b2,
    const float* __restrict__ Xin,
    const float* __restrict__ ln2w, const float* __restrict__ ln2b,
    const float* __restrict__ ln1w, const float* __restrict__ ln1b,
    float* __restrict__ Xout,
    const u16* __restrict__ Wq,   // next layer qkvg weights (nullptr on last layer)
    u16* __restrict__ Qo, u16* __restrict__ Ko,
    u16* __restrict__ Vto, u16* __restrict__ Go,
    const u16* __restrict__ DecW1, const float* __restrict__ db1,
    const float* __restrict__ dw2, const float* __restrict__ db2,
    float* __restrict__ outp)
{
  __shared__ u16 smem[33280];      // bufA[16384] bufB[16384] sRed[512 u16 = 256 f32]
  u16* bufA = smem;
  u16* bufB = smem + 16384;
  float (*sRed)[2][2] = (float(*)[2][2])(smem + 32768);
  int t=threadIdx.x, lane=t&63, wid=t>>6, mrow=lane&15, quad=lane>>4;
  int rg=wid>>1, half=wid&1;
  int r0=rg*16, c0=half*64;
  // complementary-lt block swizzle (round-10 win; bijective over (b,lt))
  int bix = blockIdx.x;
  int kk = (bix>>6)&3, hib = bix>>8;
  int ltsw = hib ? (7-kk) : kk;
  int tok0 = (((bix&63)<<3) | ltsw) * 64;
  int srow = lane>>4, phys16l = lane&15;

  // ================= Phase R: retention, 2 head-pairs =================
  int half8 = wid>>2, lw = wid&3;     // half-block id, local wave in half
  int tl = t & 255;                   // local thread id in half
  int r0l = lw*16;
  int lt = (tok0>>6)&7;               // lt tile index within sequence
  int bq = tok0>>9;                   // batch index
  bf16x8 gfrag[8];

  #pragma unroll
  for(int p=0;p<2;p++){
    int n = 2*p + half8;
    int bn = bq*4 + n;
    float lg2g = (n==0)?l2g.x:(n==1)?l2g.y:(n==2)?l2g.z:l2g.w;
    u16* rK = smem + half8*12544;     // [64] stride 44
    u16* rV = rK + 2816;              // [64] stride 76
    u16* rS = rK + 7680;              // [64] stride 76

    bf16x8 qa = *(const bf16x8*)&Qin[((size_t)bn*512 + lt*64 + r0l+mrow)*32 + quad*8];
    f32x4 oacc[4];
    #pragma unroll
    for(int cc=0;cc<4;cc++) oacc[cc] = (f32x4){0.f,0.f,0.f,0.f};
    float gp1 = exp2f(lg2g), gp2 = gp1*gp1, gp3 = gp2*gp1;
    float gpow[4] = {1.f, gp1, gp2, gp3};
    float gw[4], gb[4];
    #pragma unroll
    for(int cc=0;cc<4;cc++){ gw[cc]=gnw[n*64+cc*16+mrow]; gb[cc]=gnb[n*64+cc*16+mrow]; }
    int rowl0 = lt*64 + r0l + quad*4;

    // T14 load-hoist: tile mt+1 in regs while tile mt computes
    int krow = tl>>2, kc8 = (tl&3)*8;
    int vrow = tl>>3, vc8 = (tl&7)*8;
    const u16* Kb = Kin  + ((size_t)bn*512 + krow)*32 + kc8;
    const u16* V0 = Vtin + ((size_t)bn*64 + vrow)*512 + vc8;
    const u16* V1 = Vtin + ((size_t)bn*64 + vrow+32)*512 + vc8;
    uint4 ldk  = *(const uint4*)(Kb);
    uint4 ldv0 = *(const uint4*)(V0);
    uint4 ldv1 = *(const uint4*)(V1);

    for(int mt=0; mt<=lt; mt++){
      if(mt) __syncthreads();
      *(uint4*)&rK[krow*44+kc8]      = ldk;
      *(uint4*)&rV[vrow*76+vc8]      = ldv0;
      *(uint4*)&rV[(vrow+32)*76+vc8] = ldv1;
      if(mt < lt){
        ldk  = *(const uint4*)(Kb + (size_t)(mt+1)*2048);
        ldv0 = *(const uint4*)(V0 + (mt+1)*64);
        ldv1 = *(const uint4*)(V1 + (mt+1)*64);
      }
      __syncthreads();
      f32x4 sacc[4];
      #pragma unroll
      for(int cc=0;cc<4;cc++){
        bf16x8 bb = *(const bf16x8*)&rK[(cc*16+mrow)*44 + quad*8];
        sacc[cc] = __builtin_amdgcn_mfma_f32_16x16x32_bf16(qa,bb,(f32x4){0.f,0.f,0.f,0.f},0,0,0);
      }
      #pragma unroll
      for(int cc=0;cc<4;cc++){
        int colm = mt*64 + cc*16 + mrow;
        int d0 = rowl0 - colm;
        float w0 = exp2f(lg2g*(float)d0);
        #pragma unroll
        for(int reg=0;reg<4;reg++){
          float w = (d0+reg>=0) ? w0*gpow[reg] : 0.f;
          rS[(r0l+quad*4+reg)*76 + cc*16+mrow] = f2bf(sacc[cc][reg]*w);
        }
      }
      __syncthreads();
      #pragma unroll
      for(int ks=0;ks<2;ks++){
        bf16x8 a = *(const bf16x8*)&rS[(r0l+mrow)*76 + ks*32+quad*8];
        #pragma unroll
        for(int cc=0;cc<4;cc++){
          bf16x8 bb = *(const bf16x8*)&rV[(cc*16+mrow)*76 + ks*32+quad*8];
          oacc[cc] = __builtin_amdgcn_mfma_f32_16x16x32_bf16(a,bb,oacc[cc],0,0,0);
        }
      }
    }

    __syncthreads();
    // GroupNorm + silu(G) gate -> gated values into rS (stride 76, v-dim cols 0..63)
    #pragma unroll
    for(int reg=0;reg<4;reg++){
      float s=0.f, sq=0.f;
      #pragma unroll
      for(int cc=0;cc<4;cc++){ float v=oacc[cc][reg]; s+=v; sq+=v*v; }
      #pragma unroll
      for(int m=1;m<16;m<<=1){ s+=__shfl_xor(s,m); sq+=__shfl_xor(sq,m); }
      float mu = s*(1.f/64.f);
      float var = sq*(1.f/64.f) - mu*mu;
      float rn = rsqrtf(var + 1e-5f);
      int rowl = r0l + quad*4 + reg;
      int l = lt*64 + rowl;
      size_t gbase = ((size_t)(bq*512 + l))*256 + n*64;
      #pragma unroll
      for(int cc=0;cc<4;cc++){
        float gg = bf2f(Gin[gbase + cc*16+mrow]);
        float gate = gg/(1.f+expf(-gg));
        rS[rowl*76 + cc*16+mrow] = f2bf(gate*((oacc[cc][reg]-mu)*rn*gw[cc] + gb[cc]));
      }
    }
    __syncthreads();
    // gfrag extraction for BOTH heads of this pair (head nn -> gfrag[2nn..2nn+1])
    #pragma unroll
    for(int hh=0; hh<2; hh++){
      int nn = 2*p + hh;
      const u16* src = smem + hh*12544 + 7680;
      #pragma unroll
      for(int ksl=0; ksl<2; ksl++)
        gfrag[2*nn+ksl] = *(const bf16x8*)&src[(r0+mrow)*76 + ksl*32 + quad*8];
    }
    __syncthreads();   // reads done before next pair / STAGE overwrites
  }

  // ================= Phase M: MLP (round-8-proven body) =================
  STAGE_TILE_N(bufA, Wo, 256, 0, wid, srow, phys16l, 4);
  __syncthreads();                               // bufA(wo-kh0) ready

  // ---- P1: wo kh0 (read bufA) | stage wo kh1 -> bufB
  STAGE_TILE_N(bufB, Wo, 256, 128, wid, srow, phys16l, 4);
  f32x4 yac[4];
  #pragma unroll
  for(int cc=0;cc<4;cc++) yac[cc]=(f32x4){0.f,0.f,0.f,0.f};
  #pragma unroll
  for(int cc=0;cc<4;cc++){
    #pragma unroll
    for(int ks=0;ks<4;ks++){
      bf16x8 b=*(const bf16x8*)&bufA[(c0+cc*16+mrow)*128 + (((ks*4+quad)^mrow)<<3)];
      yac[cc]=__builtin_amdgcn_mfma_f32_16x16x32_bf16(gfrag[ks],b,yac[cc],0,0,0);
    }
  }
  __syncthreads();                               // bufA reads done; bufB drained

  // ---- P2: wo kh1 (read bufB) | stage ffn1-nh0 -> bufA ; LN2 partials
  STAGE_TILE_N(bufA, W1t, 128, 0, wid, srow, phys16l, 4);
  #pragma unroll
  for(int cc=0;cc<4;cc++){
    #pragma unroll
    for(int ks=0;ks<4;ks++){
      bf16x8 b=*(const bf16x8*)&bufB[(c0+cc*16+mrow)*128 + (((ks*4+quad)^mrow)<<3)];
      yac[cc]=__builtin_amdgcn_mfma_f32_16x16x32_bf16(gfrag[4+ks],b,yac[cc],0,0,0);
    }
  }
  float yv[4][4];
  #pragma unroll
  for(int reg=0;reg<4;reg++){
    int rowl=r0+quad*4+reg, rowg=tok0+rowl;
    float s=0.f, sq=0.f;
    #pragma unroll
    for(int cc=0;cc<4;cc++){
      float v=yac[cc][reg]+Xin[(size_t)rowg*128+c0+cc*16+mrow];
      yv[cc][reg]=v; s+=v; sq+=v*v;
    }
    #pragma unroll
    for(int m=1;m<16;m<<=1){ s+=__shfl_xor(s,m); sq+=__shfl_xor(sq,m); }
    if(mrow==0){ sRed[rowl][half][0]=s; sRed[rowl][half][1]=sq; }
  }
  __syncthreads();                               // bufB reads done; sRed ready; bufA drained

  // ---- LN2 finish: Z -> bufB (dead; stride 136)
  #pragma unroll
  for(int reg=0;reg<4;reg++){
    int rowl=r0+quad*4+reg;
    float s =sRed[rowl][0][0]+sRed[rowl][1][0];
    float sq=sRed[rowl][0][1]+sRed[rowl][1][1];
    float mu=s*(1.f/128.f);
    float var=sq*(1.f/128.f)-mu*mu;
    float rstd=rsqrtf(var+1e-5f);
    #pragma unroll
    for(int cc=0;cc<4;cc++){
      int col=c0+cc*16+mrow;
      bufB[rowl*136+col]=f2bf((yv[cc][reg]-mu)*rstd*ln2w[col]+ln2b[col]);
    }
  }
  __syncthreads();
  bf16x8 az[4];
  #pragma unroll
  for(int ks=0;ks<4;ks++) az[ks]=*(const bf16x8*)&bufB[(r0+mrow)*136+ks*32+quad*8];
  __syncthreads();                               // az reads done -> bufB stageable

  // ---- P3: ffn1 nh0 (read bufA) | stage ffn1-nh1 -> bufB ; H0 via dead bufA
  bf16x8 hfrag[8];
  STAGE_TILE_N(bufB, W1t + (size_t)16384, 128, 0, wid, srow, phys16l, 4);
  {
    f32x4 hac[4];
    #pragma unroll
    for(int cc=0;cc<4;cc++) hac[cc]=(f32x4){0.f,0.f,0.f,0.f};
    #pragma unroll
    for(int cc=0;cc<4;cc++){
      #pragma unroll
      for(int ks=0;ks<4;ks++){
        bf16x8 b=*(const bf16x8*)&bufA[(c0+cc*16+mrow)*128 + (((ks*4+quad)^mrow)<<3)];
        hac[cc]=__builtin_amdgcn_mfma_f32_16x16x32_bf16(az[ks],b,hac[cc],0,0,0);
      }
    }
    __syncthreads();                             // bufA reads done; bufB drained
    #pragma unroll
    for(int cc=0;cc<4;cc++){
      float bs=b1[c0+cc*16+mrow];
      #pragma unroll
      for(int reg=0;reg<4;reg++)
        bufA[(r0+quad*4+reg)*136 + c0+cc*16+mrow]=f2bf(gelu_f(hac[cc][reg]+bs));
    }
    __syncthreads();
    #pragma unroll
    for(int ks=0;ks<4;ks++) hfrag[ks]=*(const bf16x8*)&bufA[(r0+mrow)*136+ks*32+quad*8];
    __syncthreads();                             // hfrag0 reads done -> bufA stageable
  }

  // ---- P4: ffn1 nh1 (read bufB) | stage ffn2-kh0 -> bufA ; H1 via dead bufB
  STAGE_TILE_N(bufA, W2t, 256, 0, wid, srow, phys16l, 4);
  {
    f32x4 hac[4];
    #pragma unroll
    for(int cc=0;cc<4;cc++) hac[cc]=(f32x4){0.f,0.f,0.f,0.f};
    #pragma unroll
    for(int cc=0;cc<4;cc++){
      #pragma unroll
      for(int ks=0;ks<4;ks++){
        bf16x8 b=*(const bf16x8*)&bufB[(c0+cc*16+mrow)*128 + (((ks*4+quad)^mrow)<<3)];
        hac[cc]=__builtin_amdgcn_mfma_f32_16x16x32_bf16(az[ks],b,hac[cc],0,0,0);
      }
    }
    __syncthreads();                             // bufB reads done; bufA drained
    #pragma unroll
    for(int cc=0;cc<4;cc++){
      float bs=b1[128+c0+cc*16+mrow];
      #pragma unroll
      for(int reg=0;reg<4;reg++)
        bufB[(r0+quad*4+reg)*136 + c0+cc*16+mrow]=f2bf(gelu_f(hac[cc][reg]+bs));
    }
    __syncthreads();
    #pragma unroll
    for(int ks=0;ks<4;ks++) hfrag[4+ks]=*(const bf16x8*)&bufB[(r0+mrow)*136+ks*32+quad*8];
    __syncthreads();                             // hfrag1 reads done -> bufB stageable
  }

  // ---- P5: ffn2 kh0 (read bufA) | stage ffn2-kh1 -> bufB
  STAGE_TILE_N(bufB, W2t, 256, 128, wid, srow, phys16l, 4);
  f32x4 xac[4];
  #pragma unroll
  for(int cc=0;cc<4;cc++) xac[cc]=(f32x4){0.f,0.f,0.f,0.f};
  #pragma unroll
  for(int cc=0;cc<4;cc++){
    #pragma unroll
    for(int ks=0;ks<4;ks++){
      bf16x8 b=*(const bf16x8*)&bufA[(c0+cc*16+mrow)*128 + (((ks*4+quad)^mrow)<<3)];
      xac[cc]=__builtin_amdgcn_mfma_f32_16x16x32_bf16(hfrag[ks],b,xac[cc],0,0,0);
    }
  }
  __syncthreads();                               // bufA reads done; bufB drained

  // ---- P6: ffn2 kh1 (read bufB) | stage qkvg-nc0 -> bufA ; epilogue partials
  if(Wq) STAGE_TILE_N(bufA, Wq, 128, 0, wid, srow, phys16l, 4);
  #pragma unroll
  for(int cc=0;cc<4;cc++){
    #pragma unroll
    for(int ks=0;ks<4;ks++){
      bf16x8 b=*(const bf16x8*)&bufB[(c0+cc*16+mrow)*128 + (((ks*4+quad)^mrow)<<3)];
      xac[cc]=__builtin_amdgcn_mfma_f32_16x16x32_bf16(hfrag[4+ks],b,xac[cc],0,0,0);
    }
  }
  float xv[4][4];
  #pragma unroll
  for(int reg=0;reg<4;reg++){
    int rowl=r0+quad*4+reg;
    float s=0.f, sq=0.f;
    #pragma unroll
    for(int cc=0;cc<4;cc++){
      float v=xac[cc][reg]+b2[c0+cc*16+mrow]+yv[cc][reg];
      xv[cc][reg]=v; s+=v; sq+=v*v;
    }
    #pragma unroll
    for(int m=1;m<16;m<<=1){ s+=__shfl_xor(s,m); sq+=__shfl_xor(sq,m); }
    if(mrow==0){ sRed[rowl][half][0]=s; sRed[rowl][half][1]=sq; }
  }
  __syncthreads();                               // bufB reads done; sRed ready; bufA drained

  if(Wq){
    // ---- epilogue: Xout stores; LN1(next) -> xn in dead bufB
    #pragma unroll
    for(int reg=0;reg<4;reg++){
      int rowl=r0+quad*4+reg, rowg=tok0+rowl;
      float s =sRed[rowl][0][0]+sRed[rowl][1][0];
      float sq=sRed[rowl][0][1]+sRed[rowl][1][1];
      float mu=s*(1.f/128.f);
      float var=sq*(1.f/128.f)-mu*mu;
      float rstd=rsqrtf(var+1e-5f);
      #pragma unroll
      for(int cc=0;cc<4;cc++){
        int col=c0+cc*16+mrow;
        Xout[(size_t)rowg*128+col]=xv[cc][reg];
        bufB[rowl*136+col]=f2bf((xv[cc][reg]-mu)*rstd*ln1w[col]+ln1b[col]);
      }
    }
    __syncthreads();
    bf16x8 aq[4];
    #pragma unroll
    for(int ks=0; ks<4; ks++)
      aq[ks] = *(const bf16x8*)&bufB[(r0+mrow)*136 + ks*32+quad*8];
    __syncthreads();                             // aq reads done -> bufB stageable

    // ---- fused qkvg: nc reads buf(nc&1); stage nc+1 into the other; epi reuses dead buf
    int b = tok0>>9, l0 = tok0&511;
    for(int nc=0; nc<6; nc++){
      u16* cur = (nc&1) ? bufB : bufA;
      u16* nxt = (nc&1) ? bufA : bufB;
      if(nc<5) STAGE_TILE_N(nxt, Wq + (size_t)(nc+1)*16384, 128, 0, wid, srow, phys16l, 4);

      f32x4 acc[4];
      #pragma unroll
      for(int cc=0;cc<4;cc++) acc[cc] = (f32x4){0.f,0.f,0.f,0.f};
      #pragma unroll
      for(int ks=0; ks<4; ks++){
        #pragma unroll
        for(int cc=0; cc<4; cc++){
          bf16x8 bb = *(const bf16x8*)&cur[(c0+cc*16+mrow)*128 + (((ks*4+quad)^mrow)<<3)];
          acc[cc] = __builtin_amdgcn_mfma_f32_16x16x32_bf16(aq[ks],bb,acc[cc],0,0,0);
        }
      }
      __syncthreads();                           // cur reads done; nxt drained
      qkvg_epi8(nc, acc, cur, t, mrow, quad, r0, c0, b, l0, tok0, Qo, Ko, Vto, Go);
      __syncthreads();                           // epi's stg(cur) reads done -> cur stageable
    }
    return;
  }

  // ================= Last layer: fused DECODER (512 threads) =================
  u16*  sWd  = smem;
  float* sHd = (float*)(smem + 8704);
  float* sw2s= (float*)(smem + 17408);
  float* sLs = (float*)(smem + 19968);
  float* sb2s= (float*)(smem + 22528);
  u16*  sXd  = smem + 24064;

  // X bf16 -> sXd (own rows/cols from regs; no Xout HBM write on last layer)
  #pragma unroll
  for(int reg=0;reg<4;reg++){
    int rowl=r0+quad*4+reg;
    #pragma unroll
    for(int cc=0;cc<4;cc++){
      int col=c0+cc*16+mrow;
      sXd[rowl*136+col]=f2bf(xv[cc][reg]);
    }
  }
  // stage dec_w1t [64][128] -> sWd stride 136 ; sw2/sb2
  for(int th=t; th<1024; th+=512){
    int row=th>>4, c8=(th&15)*8;
    *(uint4*)&sWd[row*136+c8] = *(const uint4*)&DecW1[(size_t)row*128 + c8];
  }
  for(int i=t;i<1280;i+=512) sw2s[i]=dw2[i];
  if(t<20) sb2s[t]=db2[t];
  __syncthreads();

  // MFMA: wave (rg,half): rows r0..r0+15, cols half*32 + cc*16, cc in {0,1}; K=128
  {
    f32x4 dacc[2];
    #pragma unroll
    for(int cc=0;cc<2;cc++) dacc[cc]=(f32x4){0.f,0.f,0.f,0.f};
    #pragma unroll
    for(int ks=0; ks<4; ks++){
      int koff = ks*32 + quad*8;
      bf16x8 a = *(const bf16x8*)&sXd[(r0+mrow)*136 + koff];
      #pragma unroll
      for(int cc=0; cc<2; cc++){
        bf16x8 b = *(const bf16x8*)&sWd[(half*32+cc*16+mrow)*136 + koff];
        dacc[cc] = __builtin_amdgcn_mfma_f32_16x16x32_bf16(a,b,dacc[cc],0,0,0);
      }
    }
    #pragma unroll
    for(int cc=0;cc<2;cc++){
      int col = half*32 + cc*16 + mrow;
      float bb = db1[col];
      #pragma unroll
      for(int reg=0;reg<4;reg++)
        sHd[(r0+quad*4+reg)*68 + col] = gelu_f(dacc[cc][reg] + bb);
    }
  }
  __syncthreads();

  for(int task=t; task<1280; task+=512){
    int tk = task/20, o = task - tk*20;
    float a = sb2s[o];
    for(int k=0;k<64;k++) a += sHd[tk*68+k]*sw2s[k*20+o];
    sLs[tk*20+o] = a;
  }
  __syncthreads();
  if(t < 64){
    float mx = -1e30f;
    #pragma unroll
    for(int o=0;o<20;o++) mx = fmaxf(mx, sLs[t*20+o]);
    float sum = 0.f;
    float e[20];
    #pragma unroll
    for(int o=0;o<20;o++){ e[o]=expf(sLs[t*20+o]-mx); sum += e[o]; }
    float inv = 1.f/sum;
    #pragma unroll
    for(int o=0;o<20;o++) sLs[t*20+o] = e[o]*inv;
  }
  __syncthreads();
  for(int th=t; th<1280; th+=512){
    outp[(size_t)tok0*20 + th] = sLs[th];
  }
}

extern "C" void kernel_launch(void* const* d_in, const int* in_sizes, int n_in,
                              void* d_out, int out_size, void* d_ws, size_t ws_size,
                              hipStream_t stream) {
  (void)in_sizes; (void)n_in; (void)out_size; (void)ws_size;
  const float* x      = (const float*)d_in[0];
  const float* rem_w1 = (const float*)d_in[1];
  const float* rem_b1 = (const float*)d_in[2];
  const float* rem_w2 = (const float*)d_in[3];
  const float* rem_b2 = (const float*)d_in[4];
  const float* rem_w3 = (const float*)d_in[5];
  const float* rem_b3 = (const float*)d_in[6];
  const float* wq     = (const float*)d_in[7];
  const float* wk     = (const float*)d_in[8];
  const float* wv     = (const float*)d_in[9];
  const float* wg     = (const float*)d_in[10];
  const float* wo     = (const float*)d_in[11];
  const float* gn_w   = (const float*)d_in[12];
  const float* gn_b   = (const float*)d_in[13];
  const float* ln1_w  = (const float*)d_in[14];
  const float* ln1_b  = (const float*)d_in[15];
  const float* ln2_w  = (const float*)d_in[16];
  const float* ln2_b  = (const float*)d_in[17];
  const float* ffn_w1 = (const float*)d_in[18];
  const float* ffn_b1 = (const float*)d_in[19];
  const float* ffn_w2 = (const float*)d_in[20];
  const float* ffn_b2 = (const float*)d_in[21];
  const float* dec_w1 = (const float*)d_in[22];
  const float* dec_b1 = (const float*)d_in[23];
  const float* dec_w2 = (const float*)d_in[24];
  const float* dec_b2 = (const float*)d_in[25];
  float* outp = (float*)d_out;

  const size_t S128 = (size_t)BT*128;
  const size_t S256 = (size_t)BT*256;
  float* ws = (float*)d_ws;
  float* Xb = ws;                        // residual X (S128 f32)
  // ping-pong set 0
  u16*  Q0  = (u16*)(Xb + S128);         // BT*32
  u16*  K0  = Q0 + (size_t)BT*32;        // BT*32
  u16*  Vt0 = K0 + (size_t)BT*32;        // BT*64
  // ping-pong set 1
  u16*  Q1  = Vt0 + (size_t)BT*64;       // BT*32
  u16*  K1  = Q1 + (size_t)BT*32;
  u16*  Vt1 = K1 + (size_t)BT*32;
  u16*  G0  = Vt1 + (size_t)BT*64;       // S256
  u16*  G1  = G0 + S256;                 // S256
  u16*  WtBf = G1 + S256;                // bf16 weights (804864 u16)

  double lgA = log(1.0/32.0), lgB = log(1.0/512.0);
  float4 l2g;
  {
    double g0 = 1.0 - exp(lgA + 0.0*(lgB-lgA)/3.0);
    double g1 = 1.0 - exp(lgA + 1.0*(lgB-lgA)/3.0);
    double g2 = 1.0 - exp(lgA + 2.0*(lgB-lgA)/3.0);
    double g3 = 1.0 - exp(lgA + 3.0*(lgB-lgA)/3.0);
    l2g.x = (float)(log(g0)/log(2.0));
    l2g.y = (float)(log(g1)/log(2.0));
    l2g.z = (float)(log(g2)/log(2.0));
    l2g.w = (float)(log(g3)/log(2.0));
  }

  wconv_kernel<<<3144, 256, 0, stream>>>(wq, wk, wv, wg, wo, ffn_w1, ffn_w2, dec_w1,
                                         rem_w2, rem_w3, WtBf);
  embed_kernel<<<BT/64, 256, 0, stream>>>(x, rem_w1, rem_b1, rem_b2, rem_b3,
                                          WtBf+794624, ln1_w, ln1_b, WtBf,
                                          Xb, Q0, K0, Vt0, G0);

  for(int li=0; li<4; li++){
    u16* Wt_l = WtBf + (size_t)li*196608;
    const float* gnw_l = gn_w + (size_t)li*VDIM;
    const float* gnb_l = gn_b + (size_t)li*VDIM;
    const float* l2w = ln2_w + (size_t)li*HID, *l2b = ln2_b + (size_t)li*HID;
    const float* f1b = ffn_b1 + (size_t)li*FFND;
    const float* f2b = ffn_b2 + (size_t)li*HID;
    int nli = (li+1)&3;
    const float* n1w = ln1_w + (size_t)nli*HID, *n1b = ln1_b + (size_t)nli*HID;
    const u16* Wq_next = (li<3) ? (WtBf + (size_t)(li+1)*196608) : nullptr;

    const u16* Qi  = (li&1) ? Q1  : Q0;
    const u16* Ki  = (li&1) ? K1  : K0;
    const u16* Vti = (li&1) ? Vt1 : Vt0;
    const u16* Gi  = (li&1) ? G1  : G0;
    u16* Qo  = (li&1) ? Q0  : Q1;
    u16* Ko  = (li&1) ? K0  : K1;
    u16* Vto = (li&1) ? Vt0 : Vt1;
    u16* Go  = (li&1) ? G0  : G1;

    layer_kernel<<<BT/64, 512, 0, stream>>>(
        Qi, Ki, Vti, Gi, gnw_l, gnb_l, l2g,
        Wt_l+98304, Wt_l+131072, f1b, Wt_l+163840, f2b,
        Xb, l2w, l2b, n1w, n1b, Xb,
        Wq_next, Qo, Ko, Vto, Go,
        WtBf+786432, dec_b1, dec_w2, dec_b2, outp);
  }
}

// Round 14
// 417.326 us; speedup vs baseline: 1.4427x; 1.4427x over previous
//
#include <hip/hip_runtime.h>
#include <math.h>
#include <cmath>

#define SEQ   512
#define NBATCH 64
#define BT    32768      // 64*512 tokens
#define HID   128
#define NHEAD 4
#define HD    32
#define VHD   64
#define VDIM  256
#define FFND  256

typedef __attribute__((ext_vector_type(8))) short bf16x8;
typedef __attribute__((ext_vector_type(4))) float f32x4;
typedef unsigned short u16;

__device__ __forceinline__ float gelu_f(float x){ return 0.5f*x*(1.f+erff(x*0.70710678118f)); }

// HW bf16 convert (compiler-native __bf16 cast; RTNE)
__device__ __forceinline__ u16 f2bf(float f){
  __bf16 h = (__bf16)f;
  union{__bf16 h; u16 u;} v; v.h = h; return v.u;
}
__device__ __forceinline__ float bf2f(u16 u){
  union{unsigned u; float f;} v; v.u = ((unsigned)u)<<16; return v.f;
}

// async 16B global->LDS (HW scatters lane i at ldsbase + i*16)
__device__ __forceinline__ void gload16(const void* g, void* l){
  __builtin_amdgcn_global_load_lds(
      (const __attribute__((address_space(1))) unsigned*)g,
      (__attribute__((address_space(3))) unsigned*)l, 16, 0, 0);
}

// stage a 128-row x 128-u16 weight tile, XOR-swizzled (phys16 = log16 ^ (row&15))
// B-frag read: logical (row, ks*32+quad*8) -> sW[row*128 + (((ks*4+quad)^(row&15))<<3)]
#define STAGE_TILE_N(dst, base, strideU16, colOffU16, wid_, srow_, phys16l_, NIT) \
  do{                                                                           \
    _Pragma("unroll")                                                           \
    for(int it_=0; it_<NIT; it_++){                                             \
      int blk_ = (wid_)*NIT + it_;                                              \
      int row_ = blk_*4 + (srow_);                                              \
      int log16_ = (phys16l_) ^ (row_&15);                                      \
      gload16((base) + (size_t)row_*(strideU16) + (colOffU16) + log16_*8,       \
              &(dst)[blk_*512]);                                                \
    }                                                                           \
  }while(0)

#define STAGE_TILE(dst, base, strideU16, colOffU16, wid_, srow_, phys16l_) \
  STAGE_TILE_N(dst, base, strideU16, colOffU16, wid_, srow_, phys16l_, 8)

// ---------------- weight convert + transpose -> bf16 Wt[N][K] ----------------
// per-layer region (196608 u16): [0)qkvg 768x128  [98304)wo 128x256  [131072)f1 256x128  [163840)f2 128x256
// tail: 786432 dec_w1t 64x128 (8192); 794624 rem_w2t 64x32 (2048); 796672 rem_w3t 128x64 (8192). total 804864
__global__ __launch_bounds__(256) void wconv_kernel(
    const float* __restrict__ wq, const float* __restrict__ wk,
    const float* __restrict__ wv, const float* __restrict__ wg,
    const float* __restrict__ wo, const float* __restrict__ f1,
    const float* __restrict__ f2, const float* __restrict__ dw1,
    const float* __restrict__ w2e, const float* __restrict__ w3e,
    u16* __restrict__ Wt)
{
  int idx = blockIdx.x*256 + threadIdx.x;   // 0..804863
  if(idx >= 786432){
    int q = idx - 786432;
    if(q < 8192){ int col=q>>7, h=q&127; Wt[idx]=f2bf(dw1[h*64+col]); }
    else if(q < 10240){ int p=q-8192; int row=p>>5, col=p&31; Wt[idx]=f2bf(w2e[col*64+row]); }
    else { int p=q-10240; int row=p>>6, col=p&63; Wt[idx]=f2bf(w3e[col*128+row]); }
    return;
  }
  int layer = idx / 196608;
  int r = idx - layer*196608;
  u16* W = Wt + (size_t)layer*196608;
  const float* wq_l = wq + (size_t)layer*16384;
  const float* wk_l = wk + (size_t)layer*16384;
  const float* wv_l = wv + (size_t)layer*32768;
  const float* wg_l = wg + (size_t)layer*32768;
  const float* wo_l = wo + (size_t)layer*32768;
  const float* f1_l = f1 + (size_t)layer*32768;
  const float* f2_l = f2 + (size_t)layer*32768;
  float v;
  if(r < 98304){
    int col = r>>7, h = r&127;
    if(col<128){ int n=col>>5, d=col&31; v = wq_l[(n*128+h)*32+d]; }
    else if(col<256){ int c=col-128, n=c>>5, d=c&31; v = wk_l[(n*128+h)*32+d]; }
    else if(col<512){ int c=col-256, n=c>>6, j=c&63; v = wv_l[(n*128+h)*64+j]; }
    else { int p=col-512; v = wg_l[h*256+p]; }
    W[r] = f2bf(v);
  } else if(r < 131072){
    int q = r-98304; int col=q>>8, k=q&255;
    W[r] = f2bf(wo_l[k*128+col]);
  } else if(r < 163840){
    int q = r-131072; int col=q>>7, h=q&127;
    W[r] = f2bf(f1_l[h*256+col]);
  } else {
    int q = r-163840; int col=q>>8, k=q&255;
    W[r] = f2bf(f2_l[k*128+col]);
  }
}

// ---------------- qkvg epilogue helper (4-wave version, used by embed_kernel) ----------------
__device__ __forceinline__ void qkvg_epilogue(
    int nc, f32x4 acc[2][4], u16* stg,
    int t, int mrow, int quad, int r0q, int c0q, int b, int l0, int tok0,
    u16* __restrict__ Q, u16* __restrict__ K,
    u16* __restrict__ Vt, u16* __restrict__ G)
{
  if(nc < 2){
    bool isK = (nc==1);
    float sgn = isK ? -1.f : 1.f;
    #pragma unroll
    for(int cc=0;cc<4;cc++){
      int colc = c0q + cc*16 + mrow;
      int i = (colc&31)>>1;
      float log2bs = log2f(((float)i + 12.8f)*(1.f/44.8f));
      float invf   = exp2f(-(float)i * (13.28771238f/16.f));
      float rstep  = exp2f(sgn*log2bs*(1.f/512.f));
      float c1 = cosf(invf), s1 = sinf(invf);
      #pragma unroll
      for(int rr=0;rr<2;rr++){
        int rowl0 = r0q + rr*16 + quad*4;
        float lb = (float)(l0 + rowl0);
        float sc = exp2f(sgn*log2bs*lb*(1.f/512.f));
        float ang = lb*invf;
        float u = cosf(ang)*sc, v = sinf(ang)*sc;
        #pragma unroll
        for(int reg=0;reg<4;reg++){
          int rowl = rowl0 + reg;
          float val = acc[rr][cc][reg];
          float partner = __shfl_xor(val, 1);
          float o = (colc&1) ? (val*u + partner*v) : (val*u - partner*v);
          stg[rowl*136 + colc] = f2bf(o);
          float un = (u*c1 - v*s1)*rstep;
          float vn = (u*s1 + v*c1)*rstep;
          u = un; v = vn;
        }
      }
    }
    __syncthreads();
    u16* O = isK ? K : Q;
    for(int th=t; th<1024; th+=256){
      int row=th>>4, n=(th>>2)&3, seg=th&3;
      *(uint4*)&O[(((size_t)(b*4+n)*512) + (l0+row))*32 + seg*8]
        = *(const uint4*)&stg[row*136 + n*32 + seg*8];
    }
  } else if(nc < 4){
    #pragma unroll
    for(int cc=0;cc<4;cc++){
      int colc = c0q + cc*16 + mrow;
      #pragma unroll
      for(int rr=0;rr<2;rr++){
        #pragma unroll
        for(int reg=0;reg<4;reg++){
          int rowl = r0q + rr*16 + quad*4 + reg;
          stg[colc*72 + rowl] = f2bf(acc[rr][cc][reg]);
        }
      }
    }
    __syncthreads();
    int jbase = (nc-2)*128;
    for(int th=t; th<1024; th+=256){
      int row=th>>3, seg=th&7;
      int jg = jbase + row; int n = jg>>6, j = jg&63;
      *(uint4*)&Vt[(((size_t)(b*4+n)*64) + j)*512 + l0 + seg*8]
        = *(const uint4*)&stg[row*72 + seg*8];
    }
  } else {
    #pragma unroll
    for(int cc=0;cc<4;cc++){
      int colc = c0q + cc*16 + mrow;
      #pragma unroll
      for(int rr=0;rr<2;rr++){
        #pragma unroll
        for(int reg=0;reg<4;reg++){
          int rowl = r0q + rr*16 + quad*4 + reg;
          stg[rowl*136 + colc] = f2bf(acc[rr][cc][reg]);
        }
      }
    }
    __syncthreads();
    int gc0 = (nc-4)*128;
    for(int th=t; th<1024; th+=256){
      int row=th>>4, seg=th&15;
      *(uint4*)&G[((size_t)(tok0+row))*256 + gc0 + seg*8]
        = *(const uint4*)&stg[row*136 + seg*8];
    }
  }
}

// ---------------- embed (MFMA) + layer-0 LN1 + FUSED layer-0 qkvg ----------------
// xn never leaves LDS: big[0..8704) holds xn (stride 136); weight chunks stage into
// big[8704..25088); epilogue staging tops out at 8704+9216=17920. All disjoint.
__global__ __launch_bounds__(256) void embed_kernel(
    const float* __restrict__ x,
    const float* __restrict__ w1, const float* __restrict__ b1,
    const float* __restrict__ b2, const float* __restrict__ b3,
    const u16* __restrict__ W23t,     // w2t[64][32] at 0, w3t[128][64] at 2048
    const float* __restrict__ lnw, const float* __restrict__ lnb,
    const u16* __restrict__ Wt,       // layer-0 qkvg weights (6 x 16384)
    float* __restrict__ X,
    u16* __restrict__ Q, u16* __restrict__ K,
    u16* __restrict__ Vt, u16* __restrict__ G)
{
  __shared__ float sx[64][6];
  __shared__ float sw1[160], sb1[32], sb2[64], sb3[128];
  __shared__ u16 big[25088];
  int t=threadIdx.x, lane=t&63, wid=t>>6, mrow=lane&15, quad=lane>>4, r0=wid*16;
  int tok0=blockIdx.x*64;

  for(int i=t;i<320;i+=256) sx[i/5][i%5]=x[(size_t)tok0*5+i];
  for(int i=t;i<160;i+=256) sw1[i]=w1[i];
  if(t<32) sb1[t]=b1[t];
  if(t<64) sb2[t]=b2[t];
  if(t<128) sb3[t]=b3[t];
  for(int c=t;c<256;c+=256){ int row=c>>2, c8=(c&3)*8;
    *(uint4*)&big[2560+row*40+c8]=*(const uint4*)&W23t[row*32+c8]; }
  for(int c=t;c<1024;c+=256){ int row=c>>3, c8=(c&7)*8;
    *(uint4*)&big[9728+row*72+c8]=*(const uint4*)&W23t[2048+row*64+c8]; }
  __syncthreads();

  for(int task=t; task<2048; task+=256){
    int tok=task>>5, j=task&31;
    float a=sb1[j];
    #pragma unroll
    for(int i=0;i<5;i++) a+=sx[tok][i]*sw1[i*32+j];
    big[tok*40+j]=f2bf(gelu_f(a));
  }
  __syncthreads();

  f32x4 h2[4];
  #pragma unroll
  for(int cc=0;cc<4;cc++) h2[cc]=(f32x4){0.f,0.f,0.f,0.f};
  {
    bf16x8 a=*(const bf16x8*)&big[(r0+mrow)*40+quad*8];
    #pragma unroll
    for(int cc=0;cc<4;cc++){
      bf16x8 b=*(const bf16x8*)&big[2560+(cc*16+mrow)*40+quad*8];
      h2[cc]=__builtin_amdgcn_mfma_f32_16x16x32_bf16(a,b,h2[cc],0,0,0);
    }
  }
  #pragma unroll
  for(int cc=0;cc<4;cc++){
    float bs=sb2[cc*16+mrow];
    #pragma unroll
    for(int reg=0;reg<4;reg++)
      big[5120+(r0+quad*4+reg)*72+cc*16+mrow]=f2bf(gelu_f(h2[cc][reg]+bs));
  }
  __syncthreads();

  f32x4 xac[8];
  #pragma unroll
  for(int cc=0;cc<8;cc++) xac[cc]=(f32x4){0.f,0.f,0.f,0.f};
  #pragma unroll
  for(int ks=0;ks<2;ks++){
    bf16x8 a=*(const bf16x8*)&big[5120+(r0+mrow)*72+ks*32+quad*8];
    #pragma unroll
    for(int cc=0;cc<8;cc++){
      bf16x8 b=*(const bf16x8*)&big[9728+(cc*16+mrow)*72+ks*32+quad*8];
      xac[cc]=__builtin_amdgcn_mfma_f32_16x16x32_bf16(a,b,xac[cc],0,0,0);
    }
  }
  __syncthreads();

  #pragma unroll
  for(int reg=0;reg<4;reg++){
    int rowl=r0+quad*4+reg, rowg=tok0+rowl;
    float xv[8], s=0.f, sq=0.f;
    #pragma unroll
    for(int cc=0;cc<8;cc++){
      float v=gelu_f(xac[cc][reg]+sb3[cc*16+mrow]);
      xv[cc]=v; s+=v; sq+=v*v;
    }
    #pragma unroll
    for(int m=1;m<16;m<<=1){ s+=__shfl_xor(s,m); sq+=__shfl_xor(sq,m); }
    float mu=s*(1.f/128.f);
    float var=sq*(1.f/128.f)-mu*mu;
    float rstd=rsqrtf(var+1e-5f);
    #pragma unroll
    for(int cc=0;cc<8;cc++){
      int col=cc*16+mrow;
      X[(size_t)rowg*128+col]=xv[cc];
      big[rowl*136+col]=f2bf((xv[cc]-mu)*rstd*lnw[col]+lnb[col]);
    }
  }
  __syncthreads();

  // ---- fused layer-0 qkvg: A-frags from xn in LDS; 6 chunks via big[8704..]
  u16* sW = big + 8704;
  u16* stg = sW;
  int srow = lane>>4, phys16l = lane&15;
  int r0q = (wid>>1)*32, c0q = (wid&1)*64;
  int b = tok0>>9, l0 = tok0&511;

  bf16x8 a0f[4], a1f[4];
  #pragma unroll
  for(int ks=0; ks<4; ks++){
    a0f[ks] = *(const bf16x8*)&big[(r0q+mrow)*136 + ks*32+quad*8];
    a1f[ks] = *(const bf16x8*)&big[(r0q+16+mrow)*136 + ks*32+quad*8];
  }
  __syncthreads();   // a-frag reads done (xn region stays intact anyway)

  for(int nc=0; nc<6; nc++){
    if(nc) __syncthreads();
    STAGE_TILE(sW, Wt + (size_t)nc*16384, 128, 0, wid, srow, phys16l);
    __syncthreads();

    f32x4 acc[2][4];
    #pragma unroll
    for(int rr=0;rr<2;rr++)
      #pragma unroll
      for(int cc=0;cc<4;cc++) acc[rr][cc] = (f32x4){0.f,0.f,0.f,0.f};
    #pragma unroll
    for(int ks=0; ks<4; ks++){
      #pragma unroll
      for(int cc=0; cc<4; cc++){
        bf16x8 bb = *(const bf16x8*)&sW[(c0q+cc*16+mrow)*128 + (((ks*4+quad)^mrow)<<3)];
        acc[0][cc] = __builtin_amdgcn_mfma_f32_16x16x32_bf16(a0f[ks],bb,acc[0][cc],0,0,0);
        acc[1][cc] = __builtin_amdgcn_mfma_f32_16x16x32_bf16(a1f[ks],bb,acc[1][cc],0,0,0);
      }
    }
    __syncthreads();
    qkvg_epilogue(nc, acc, stg, t, mrow, quad, r0q, c0q, b, l0, tok0, Q, K, Vt, G);
  }
}

// ---------------- qkvg epilogue helper (8-wave version, used by layer_kernel) ----------------
__device__ __forceinline__ void qkvg_epi8(
    int nc, f32x4 acc[4], u16* stg,
    int t, int mrow, int quad, int r0, int c0, int b, int l0, int tok0,
    u16* __restrict__ Q, u16* __restrict__ K,
    u16* __restrict__ Vt, u16* __restrict__ G)
{
  if(nc < 2){
    bool isK = (nc==1);
    float sgn = isK ? -1.f : 1.f;
    #pragma unroll
    for(int cc=0;cc<4;cc++){
      int colc = c0 + cc*16 + mrow;
      int i = (colc&31)>>1;
      float log2bs = log2f(((float)i + 12.8f)*(1.f/44.8f));
      float invf   = exp2f(-(float)i * (13.28771238f/16.f));
      float rstep  = exp2f(sgn*log2bs*(1.f/512.f));
      float c1 = cosf(invf), s1 = sinf(invf);
      int rowl0 = r0 + quad*4;
      float lb = (float)(l0 + rowl0);
      float sc = exp2f(sgn*log2bs*lb*(1.f/512.f));
      float ang = lb*invf;
      float u = cosf(ang)*sc, v = sinf(ang)*sc;
      #pragma unroll
      for(int reg=0;reg<4;reg++){
        int rowl = rowl0 + reg;
        float val = acc[cc][reg];
        float partner = __shfl_xor(val, 1);
        float o = (colc&1) ? (val*u + partner*v) : (val*u - partner*v);
        stg[rowl*136 + colc] = f2bf(o);
        float un = (u*c1 - v*s1)*rstep;
        float vn = (u*s1 + v*c1)*rstep;
        u = un; v = vn;
      }
    }
    __syncthreads();
    u16* O = isK ? K : Q;
    for(int th=t; th<1024; th+=512){
      int row=th>>4, n=(th>>2)&3, seg=th&3;
      *(uint4*)&O[(((size_t)(b*4+n)*512) + (l0+row))*32 + seg*8]
        = *(const uint4*)&stg[row*136 + n*32 + seg*8];
    }
  } else if(nc < 4){
    #pragma unroll
    for(int cc=0;cc<4;cc++){
      int colc = c0 + cc*16 + mrow;
      #pragma unroll
      for(int reg=0;reg<4;reg++){
        int rowl = r0 + quad*4 + reg;
        stg[colc*72 + rowl] = f2bf(acc[cc][reg]);
      }
    }
    __syncthreads();
    int jbase = (nc-2)*128;
    for(int th=t; th<1024; th+=512){
      int row=th>>3, seg=th&7;
      int jg = jbase + row; int n = jg>>6, j = jg&63;
      *(uint4*)&Vt[(((size_t)(b*4+n)*64) + j)*512 + l0 + seg*8]
        = *(const uint4*)&stg[row*72 + seg*8];
    }
  } else {
    #pragma unroll
    for(int cc=0;cc<4;cc++){
      int colc = c0 + cc*16 + mrow;
      #pragma unroll
      for(int reg=0;reg<4;reg++){
        int rowl = r0 + quad*4 + reg;
        stg[rowl*136 + colc] = f2bf(acc[cc][reg]);
      }
    }
    __syncthreads();
    int gc0 = (nc-4)*128;
    for(int th=t; th<1024; th+=512){
      int row=th>>4, seg=th&15;
      *(uint4*)&G[((size_t)(tok0+row))*256 + gc0 + seg*8]
        = *(const uint4*)&stg[row*136 + seg*8];
    }
  }
}

// ---------------- fused LAYER kernel: retention (4 heads) + MLP + qkvg(next) / dec(last) ----------------
// Ret LDS strides at round-11-proven 40/72 (16B-aligned rows for b128; the
// round-12 padding to 44/76 broke ds_*_b128 alignment and regressed 1.7x).
__global__ __launch_bounds__(512, 4) void layer_kernel(
    const u16* __restrict__ Qin, const u16* __restrict__ Kin,
    const u16* __restrict__ Vtin, const u16* __restrict__ Gin,
    const float* __restrict__ gnw, const float* __restrict__ gnb, float4 l2g,
    const u16* __restrict__ Wo,
    const u16* __restrict__ W1t, const float* __restrict__ b1,
    const u16* __restrict__ W2t, const float* __restrict__ b2,
    const float* __restrict__ Xin,
    const float* __restrict__ ln2w, const float* __restrict__ ln2b,
    const float* __restrict__ ln1w, const float* __restrict__ ln1b,
    float* __restrict__ Xout,
    const u16* __restrict__ Wq,   // next layer qkvg weights (nullptr on last layer)
    u16* __restrict__ Qo, u16* __restrict__ Ko,
    u16* __restrict__ Vto, u16* __restrict__ Go,
    const u16* __restrict__ DecW1, const float* __restrict__ db1,
    const float* __restrict__ dw2, const float* __restrict__ db2,
    float* __restrict__ outp)
{
  __shared__ u16 smem[33280];      // bufA[16384] bufB[16384] sRed[512 u16 = 256 f32]
  u16* bufA = smem;
  u16* bufB = smem + 16384;
  float (*sRed)[2][2] = (float(*)[2][2])(smem + 32768);
  int t=threadIdx.x, lane=t&63, wid=t>>6, mrow=lane&15, quad=lane>>4;
  int rg=wid>>1, half=wid&1;
  int r0=rg*16, c0=half*64;
  // complementary-lt block swizzle (round-10 win; bijective over (b,lt))
  int bix = blockIdx.x;
  int kk = (bix>>6)&3, hib = bix>>8;
  int ltsw = hib ? (7-kk) : kk;
  int tok0 = (((bix&63)<<3) | ltsw) * 64;
  int srow = lane>>4, phys16l = lane&15;

  // ================= Phase R: retention, 2 head-pairs =================
  int half8 = wid>>2, lw = wid&3;     // half-block id, local wave in half
  int tl = t & 255;                   // local thread id in half
  int r0l = lw*16;
  int lt = (tok0>>6)&7;               // lt tile index within sequence
  int bq = tok0>>9;                   // batch index
  bf16x8 gfrag[8];

  #pragma unroll
  for(int p=0;p<2;p++){
    int n = 2*p + half8;
    int bn = bq*4 + n;
    float lg2g = (n==0)?l2g.x:(n==1)?l2g.y:(n==2)?l2g.z:l2g.w;
    u16* rK = smem + half8*11776;     // [64] stride 40
    u16* rV = rK + 2560;              // [64] stride 72
    u16* rS = rK + 7168;              // [64] stride 72

    bf16x8 qa = *(const bf16x8*)&Qin[((size_t)bn*512 + lt*64 + r0l+mrow)*32 + quad*8];
    f32x4 oacc[4];
    #pragma unroll
    for(int cc=0;cc<4;cc++) oacc[cc] = (f32x4){0.f,0.f,0.f,0.f};
    float gp1 = exp2f(lg2g), gp2 = gp1*gp1, gp3 = gp2*gp1;
    float gpow[4] = {1.f, gp1, gp2, gp3};
    float gw[4], gb[4];
    #pragma unroll
    for(int cc=0;cc<4;cc++){ gw[cc]=gnw[n*64+cc*16+mrow]; gb[cc]=gnb[n*64+cc*16+mrow]; }
    int rowl0 = lt*64 + r0l + quad*4;

    // T14 load-hoist: tile mt+1 in regs while tile mt computes
    int krow = tl>>2, kc8 = (tl&3)*8;
    int vrow = tl>>3, vc8 = (tl&7)*8;
    const u16* Kb = Kin  + ((size_t)bn*512 + krow)*32 + kc8;
    const u16* V0 = Vtin + ((size_t)bn*64 + vrow)*512 + vc8;
    const u16* V1 = Vtin + ((size_t)bn*64 + vrow+32)*512 + vc8;
    uint4 ldk  = *(const uint4*)(Kb);
    uint4 ldv0 = *(const uint4*)(V0);
    uint4 ldv1 = *(const uint4*)(V1);

    for(int mt=0; mt<=lt; mt++){
      if(mt) __syncthreads();
      *(uint4*)&rK[krow*40+kc8]      = ldk;
      *(uint4*)&rV[vrow*72+vc8]      = ldv0;
      *(uint4*)&rV[(vrow+32)*72+vc8] = ldv1;
      if(mt < lt){
        ldk  = *(const uint4*)(Kb + (size_t)(mt+1)*2048);
        ldv0 = *(const uint4*)(V0 + (mt+1)*64);
        ldv1 = *(const uint4*)(V1 + (mt+1)*64);
      }
      __syncthreads();
      f32x4 sacc[4];
      #pragma unroll
      for(int cc=0;cc<4;cc++){
        bf16x8 bb = *(const bf16x8*)&rK[(cc*16+mrow)*40 + quad*8];
        sacc[cc] = __builtin_amdgcn_mfma_f32_16x16x32_bf16(qa,bb,(f32x4){0.f,0.f,0.f,0.f},0,0,0);
      }
      #pragma unroll
      for(int cc=0;cc<4;cc++){
        int colm = mt*64 + cc*16 + mrow;
        int d0 = rowl0 - colm;
        float w0 = exp2f(lg2g*(float)d0);
        #pragma unroll
        for(int reg=0;reg<4;reg++){
          float w = (d0+reg>=0) ? w0*gpow[reg] : 0.f;
          rS[(r0l+quad*4+reg)*72 + cc*16+mrow] = f2bf(sacc[cc][reg]*w);
        }
      }
      __syncthreads();
      #pragma unroll
      for(int ks=0;ks<2;ks++){
        bf16x8 a = *(const bf16x8*)&rS[(r0l+mrow)*72 + ks*32+quad*8];
        #pragma unroll
        for(int cc=0;cc<4;cc++){
          bf16x8 bb = *(const bf16x8*)&rV[(cc*16+mrow)*72 + ks*32+quad*8];
          oacc[cc] = __builtin_amdgcn_mfma_f32_16x16x32_bf16(a,bb,oacc[cc],0,0,0);
        }
      }
    }

    __syncthreads();
    // GroupNorm + silu(G) gate -> gated values into rS (stride 72, v-dim cols 0..63)
    #pragma unroll
    for(int reg=0;reg<4;reg++){
      float s=0.f, sq=0.f;
      #pragma unroll
      for(int cc=0;cc<4;cc++){ float v=oacc[cc][reg]; s+=v; sq+=v*v; }
      #pragma unroll
      for(int m=1;m<16;m<<=1){ s+=__shfl_xor(s,m); sq+=__shfl_xor(sq,m); }
      float mu = s*(1.f/64.f);
      float var = sq*(1.f/64.f) - mu*mu;
      float rn = rsqrtf(var + 1e-5f);
      int rowl = r0l + quad*4 + reg;
      int l = lt*64 + rowl;
      size_t gbase = ((size_t)(bq*512 + l))*256 + n*64;
      #pragma unroll
      for(int cc=0;cc<4;cc++){
        float gg = bf2f(Gin[gbase + cc*16+mrow]);
        float gate = gg/(1.f+expf(-gg));
        rS[rowl*72 + cc*16+mrow] = f2bf(gate*((oacc[cc][reg]-mu)*rn*gw[cc] + gb[cc]));
      }
    }
    __syncthreads();
    // gfrag extraction for BOTH heads of this pair (head nn -> gfrag[2nn..2nn+1])
    #pragma unroll
    for(int hh=0; hh<2; hh++){
      int nn = 2*p + hh;
      const u16* src = smem + hh*11776 + 7168;
      #pragma unroll
      for(int ksl=0; ksl<2; ksl++)
        gfrag[2*nn+ksl] = *(const bf16x8*)&src[(r0+mrow)*72 + ksl*32 + quad*8];
    }
    __syncthreads();   // reads done before next pair / STAGE overwrites
  }

  // ================= Phase M: MLP (round-8-proven body) =================
  STAGE_TILE_N(bufA, Wo, 256, 0, wid, srow, phys16l, 4);
  __syncthreads();                               // bufA(wo-kh0) ready

  // ---- P1: wo kh0 (read bufA) | stage wo kh1 -> bufB
  STAGE_TILE_N(bufB, Wo, 256, 128, wid, srow, phys16l, 4);
  f32x4 yac[4];
  #pragma unroll
  for(int cc=0;cc<4;cc++) yac[cc]=(f32x4){0.f,0.f,0.f,0.f};
  #pragma unroll
  for(int cc=0;cc<4;cc++){
    #pragma unroll
    for(int ks=0;ks<4;ks++){
      bf16x8 b=*(const bf16x8*)&bufA[(c0+cc*16+mrow)*128 + (((ks*4+quad)^mrow)<<3)];
      yac[cc]=__builtin_amdgcn_mfma_f32_16x16x32_bf16(gfrag[ks],b,yac[cc],0,0,0);
    }
  }
  __syncthreads();                               // bufA reads done; bufB drained

  // ---- P2: wo kh1 (read bufB) | stage ffn1-nh0 -> bufA ; LN2 partials
  STAGE_TILE_N(bufA, W1t, 128, 0, wid, srow, phys16l, 4);
  #pragma unroll
  for(int cc=0;cc<4;cc++){
    #pragma unroll
    for(int ks=0;ks<4;ks++){
      bf16x8 b=*(const bf16x8*)&bufB[(c0+cc*16+mrow)*128 + (((ks*4+quad)^mrow)<<3)];
      yac[cc]=__builtin_amdgcn_mfma_f32_16x16x32_bf16(gfrag[4+ks],b,yac[cc],0,0,0);
    }
  }
  float yv[4][4];
  #pragma unroll
  for(int reg=0;reg<4;reg++){
    int rowl=r0+quad*4+reg, rowg=tok0+rowl;
    float s=0.f, sq=0.f;
    #pragma unroll
    for(int cc=0;cc<4;cc++){
      float v=yac[cc][reg]+Xin[(size_t)rowg*128+c0+cc*16+mrow];
      yv[cc][reg]=v; s+=v; sq+=v*v;
    }
    #pragma unroll
    for(int m=1;m<16;m<<=1){ s+=__shfl_xor(s,m); sq+=__shfl_xor(sq,m); }
    if(mrow==0){ sRed[rowl][half][0]=s; sRed[rowl][half][1]=sq; }
  }
  __syncthreads();                               // bufB reads done; sRed ready; bufA drained

  // ---- LN2 finish: Z -> bufB (dead; stride 136)
  #pragma unroll
  for(int reg=0;reg<4;reg++){
    int rowl=r0+quad*4+reg;
    float s =sRed[rowl][0][0]+sRed[rowl][1][0];
    float sq=sRed[rowl][0][1]+sRed[rowl][1][1];
    float mu=s*(1.f/128.f);
    float var=sq*(1.f/128.f)-mu*mu;
    float rstd=rsqrtf(var+1e-5f);
    #pragma unroll
    for(int cc=0;cc<4;cc++){
      int col=c0+cc*16+mrow;
      bufB[rowl*136+col]=f2bf((yv[cc][reg]-mu)*rstd*ln2w[col]+ln2b[col]);
    }
  }
  __syncthreads();
  bf16x8 az[4];
  #pragma unroll
  for(int ks=0;ks<4;ks++) az[ks]=*(const bf16x8*)&bufB[(r0+mrow)*136+ks*32+quad*8];
  __syncthreads();                               // az reads done -> bufB stageable

  // ---- P3: ffn1 nh0 (read bufA) | stage ffn1-nh1 -> bufB ; H0 via dead bufA
  bf16x8 hfrag[8];
  STAGE_TILE_N(bufB, W1t + (size_t)16384, 128, 0, wid, srow, phys16l, 4);
  {
    f32x4 hac[4];
    #pragma unroll
    for(int cc=0;cc<4;cc++) hac[cc]=(f32x4){0.f,0.f,0.f,0.f};
    #pragma unroll
    for(int cc=0;cc<4;cc++){
      #pragma unroll
      for(int ks=0;ks<4;ks++){
        bf16x8 b=*(const bf16x8*)&bufA[(c0+cc*16+mrow)*128 + (((ks*4+quad)^mrow)<<3)];
        hac[cc]=__builtin_amdgcn_mfma_f32_16x16x32_bf16(az[ks],b,hac[cc],0,0,0);
      }
    }
    __syncthreads();                             // bufA reads done; bufB drained
    #pragma unroll
    for(int cc=0;cc<4;cc++){
      float bs=b1[c0+cc*16+mrow];
      #pragma unroll
      for(int reg=0;reg<4;reg++)
        bufA[(r0+quad*4+reg)*136 + c0+cc*16+mrow]=f2bf(gelu_f(hac[cc][reg]+bs));
    }
    __syncthreads();
    #pragma unroll
    for(int ks=0;ks<4;ks++) hfrag[ks]=*(const bf16x8*)&bufA[(r0+mrow)*136+ks*32+quad*8];
    __syncthreads();                             // hfrag0 reads done -> bufA stageable
  }

  // ---- P4: ffn1 nh1 (read bufB) | stage ffn2-kh0 -> bufA ; H1 via dead bufB
  STAGE_TILE_N(bufA, W2t, 256, 0, wid, srow, phys16l, 4);
  {
    f32x4 hac[4];
    #pragma unroll
    for(int cc=0;cc<4;cc++) hac[cc]=(f32x4){0.f,0.f,0.f,0.f};
    #pragma unroll
    for(int cc=0;cc<4;cc++){
      #pragma unroll
      for(int ks=0;ks<4;ks++){
        bf16x8 b=*(const bf16x8*)&bufB[(c0+cc*16+mrow)*128 + (((ks*4+quad)^mrow)<<3)];
        hac[cc]=__builtin_amdgcn_mfma_f32_16x16x32_bf16(az[ks],b,hac[cc],0,0,0);
      }
    }
    __syncthreads();                             // bufB reads done; bufA drained
    #pragma unroll
    for(int cc=0;cc<4;cc++){
      float bs=b1[128+c0+cc*16+mrow];
      #pragma unroll
      for(int reg=0;reg<4;reg++)
        bufB[(r0+quad*4+reg)*136 + c0+cc*16+mrow]=f2bf(gelu_f(hac[cc][reg]+bs));
    }
    __syncthreads();
    #pragma unroll
    for(int ks=0;ks<4;ks++) hfrag[4+ks]=*(const bf16x8*)&bufB[(r0+mrow)*136+ks*32+quad*8];
    __syncthreads();                             // hfrag1 reads done -> bufB stageable
  }

  // ---- P5: ffn2 kh0 (read bufA) | stage ffn2-kh1 -> bufB
  STAGE_TILE_N(bufB, W2t, 256, 128, wid, srow, phys16l, 4);
  f32x4 xac[4];
  #pragma unroll
  for(int cc=0;cc<4;cc++) xac[cc]=(f32x4){0.f,0.f,0.f,0.f};
  #pragma unroll
  for(int cc=0;cc<4;cc++){
    #pragma unroll
    for(int ks=0;ks<4;ks++){
      bf16x8 b=*(const bf16x8*)&bufA[(c0+cc*16+mrow)*128 + (((ks*4+quad)^mrow)<<3)];
      xac[cc]=__builtin_amdgcn_mfma_f32_16x16x32_bf16(hfrag[ks],b,xac[cc],0,0,0);
    }
  }
  __syncthreads();                               // bufA reads done; bufB drained

  // ---- P6: ffn2 kh1 (read bufB) | stage qkvg-nc0 -> bufA ; epilogue partials
  if(Wq) STAGE_TILE_N(bufA, Wq, 128, 0, wid, srow, phys16l, 4);
  #pragma unroll
  for(int cc=0;cc<4;cc++){
    #pragma unroll
    for(int ks=0;ks<4;ks++){
      bf16x8 b=*(const bf16x8*)&bufB[(c0+cc*16+mrow)*128 + (((ks*4+quad)^mrow)<<3)];
      xac[cc]=__builtin_amdgcn_mfma_f32_16x16x32_bf16(hfrag[4+ks],b,xac[cc],0,0,0);
    }
  }
  float xv[4][4];
  #pragma unroll
  for(int reg=0;reg<4;reg++){
    int rowl=r0+quad*4+reg;
    float s=0.f, sq=0.f;
    #pragma unroll
    for(int cc=0;cc<4;cc++){
      float v=xac[cc][reg]+b2[c0+cc*16+mrow]+yv[cc][reg];
      xv[cc][reg]=v; s+=v; sq+=v*v;
    }
    #pragma unroll
    for(int m=1;m<16;m<<=1){ s+=__shfl_xor(s,m); sq+=__shfl_xor(sq,m); }
    if(mrow==0){ sRed[rowl][half][0]=s; sRed[rowl][half][1]=sq; }
  }
  __syncthreads();                               // bufB reads done; sRed ready; bufA drained

  if(Wq){
    // ---- epilogue: Xout stores; LN1(next) -> xn in dead bufB
    #pragma unroll
    for(int reg=0;reg<4;reg++){
      int rowl=r0+quad*4+reg, rowg=tok0+rowl;
      float s =sRed[rowl][0][0]+sRed[rowl][1][0];
      float sq=sRed[rowl][0][1]+sRed[rowl][1][1];
      float mu=s*(1.f/128.f);
      float var=sq*(1.f/128.f)-mu*mu;
      float rstd=rsqrtf(var+1e-5f);
      #pragma unroll
      for(int cc=0;cc<4;cc++){
        int col=c0+cc*16+mrow;
        Xout[(size_t)rowg*128+col]=xv[cc][reg];
        bufB[rowl*136+col]=f2bf((xv[cc][reg]-mu)*rstd*ln1w[col]+ln1b[col]);
      }
    }
    __syncthreads();
    bf16x8 aq[4];
    #pragma unroll
    for(int ks=0; ks<4; ks++)
      aq[ks] = *(const bf16x8*)&bufB[(r0+mrow)*136 + ks*32+quad*8];
    __syncthreads();                             // aq reads done -> bufB stageable

    // ---- fused qkvg: nc reads buf(nc&1); stage nc+1 into the other; epi reuses dead buf
    int b = tok0>>9, l0 = tok0&511;
    for(int nc=0; nc<6; nc++){
      u16* cur = (nc&1) ? bufB : bufA;
      u16* nxt = (nc&1) ? bufA : bufB;
      if(nc<5) STAGE_TILE_N(nxt, Wq + (size_t)(nc+1)*16384, 128, 0, wid, srow, phys16l, 4);

      f32x4 acc[4];
      #pragma unroll
      for(int cc=0;cc<4;cc++) acc[cc] = (f32x4){0.f,0.f,0.f,0.f};
      #pragma unroll
      for(int ks=0; ks<4; ks++){
        #pragma unroll
        for(int cc=0; cc<4; cc++){
          bf16x8 bb = *(const bf16x8*)&cur[(c0+cc*16+mrow)*128 + (((ks*4+quad)^mrow)<<3)];
          acc[cc] = __builtin_amdgcn_mfma_f32_16x16x32_bf16(aq[ks],bb,acc[cc],0,0,0);
        }
      }
      __syncthreads();                           // cur reads done; nxt drained
      qkvg_epi8(nc, acc, cur, t, mrow, quad, r0, c0, b, l0, tok0, Qo, Ko, Vto, Go);
      __syncthreads();                           // epi's stg(cur) reads done -> cur stageable
    }
    return;
  }

  // ================= Last layer: fused DECODER (512 threads) =================
  u16*  sWd  = smem;
  float* sHd = (float*)(smem + 8704);
  float* sw2s= (float*)(smem + 17408);
  float* sLs = (float*)(smem + 19968);
  float* sb2s= (float*)(smem + 22528);
  u16*  sXd  = smem + 24064;

  // X bf16 -> sXd (own rows/cols from regs; no Xout HBM write on last layer)
  #pragma unroll
  for(int reg=0;reg<4;reg++){
    int rowl=r0+quad*4+reg;
    #pragma unroll
    for(int cc=0;cc<4;cc++){
      int col=c0+cc*16+mrow;
      sXd[rowl*136+col]=f2bf(xv[cc][reg]);
    }
  }
  // stage dec_w1t [64][128] -> sWd stride 136 ; sw2/sb2
  for(int th=t; th<1024; th+=512){
    int row=th>>4, c8=(th&15)*8;
    *(uint4*)&sWd[row*136+c8] = *(const uint4*)&DecW1[(size_t)row*128 + c8];
  }
  for(int i=t;i<1280;i+=512) sw2s[i]=dw2[i];
  if(t<20) sb2s[t]=db2[t];
  __syncthreads();

  // MFMA: wave (rg,half): rows r0..r0+15, cols half*32 + cc*16, cc in {0,1}; K=128
  {
    f32x4 dacc[2];
    #pragma unroll
    for(int cc=0;cc<2;cc++) dacc[cc]=(f32x4){0.f,0.f,0.f,0.f};
    #pragma unroll
    for(int ks=0; ks<4; ks++){
      int koff = ks*32 + quad*8;
      bf16x8 a = *(const bf16x8*)&sXd[(r0+mrow)*136 + koff];
      #pragma unroll
      for(int cc=0; cc<2; cc++){
        bf16x8 b = *(const bf16x8*)&sWd[(half*32+cc*16+mrow)*136 + koff];
        dacc[cc] = __builtin_amdgcn_mfma_f32_16x16x32_bf16(a,b,dacc[cc],0,0,0);
      }
    }
    #pragma unroll
    for(int cc=0;cc<2;cc++){
      int col = half*32 + cc*16 + mrow;
      float bb = db1[col];
      #pragma unroll
      for(int reg=0;reg<4;reg++)
        sHd[(r0+quad*4+reg)*68 + col] = gelu_f(dacc[cc][reg] + bb);
    }
  }
  __syncthreads();

  for(int task=t; task<1280; task+=512){
    int tk = task/20, o = task - tk*20;
    float a = sb2s[o];
    for(int k=0;k<64;k++) a += sHd[tk*68+k]*sw2s[k*20+o];
    sLs[tk*20+o] = a;
  }
  __syncthreads();
  if(t < 64){
    float mx = -1e30f;
    #pragma unroll
    for(int o=0;o<20;o++) mx = fmaxf(mx, sLs[t*20+o]);
    float sum = 0.f;
    float e[20];
    #pragma unroll
    for(int o=0;o<20;o++){ e[o]=expf(sLs[t*20+o]-mx); sum += e[o]; }
    float inv = 1.f/sum;
    #pragma unroll
    for(int o=0;o<20;o++) sLs[t*20+o] = e[o]*inv;
  }
  __syncthreads();
  for(int th=t; th<1280; th+=512){
    outp[(size_t)tok0*20 + th] = sLs[th];
  }
}

extern "C" void kernel_launch(void* const* d_in, const int* in_sizes, int n_in,
                              void* d_out, int out_size, void* d_ws, size_t ws_size,
                              hipStream_t stream) {
  (void)in_sizes; (void)n_in; (void)out_size; (void)ws_size;
  const float* x      = (const float*)d_in[0];
  const float* rem_w1 = (const float*)d_in[1];
  const float* rem_b1 = (const float*)d_in[2];
  const float* rem_w2 = (const float*)d_in[3];
  const float* rem_b2 = (const float*)d_in[4];
  const float* rem_w3 = (const float*)d_in[5];
  const float* rem_b3 = (const float*)d_in[6];
  const float* wq     = (const float*)d_in[7];
  const float* wk     = (const float*)d_in[8];
  const float* wv     = (const float*)d_in[9];
  const float* wg     = (const float*)d_in[10];
  const float* wo     = (const float*)d_in[11];
  const float* gn_w   = (const float*)d_in[12];
  const float* gn_b   = (const float*)d_in[13];
  const float* ln1_w  = (const float*)d_in[14];
  const float* ln1_b  = (const float*)d_in[15];
  const float* ln2_w  = (const float*)d_in[16];
  const float* ln2_b  = (const float*)d_in[17];
  const float* ffn_w1 = (const float*)d_in[18];
  const float* ffn_b1 = (const float*)d_in[19];
  const float* ffn_w2 = (const float*)d_in[20];
  const float* ffn_b2 = (const float*)d_in[21];
  const float* dec_w1 = (const float*)d_in[22];
  const float* dec_b1 = (const float*)d_in[23];
  const float* dec_w2 = (const float*)d_in[24];
  const float* dec_b2 = (const float*)d_in[25];
  float* outp = (float*)d_out;

  const size_t S128 = (size_t)BT*128;
  const size_t S256 = (size_t)BT*256;
  float* ws = (float*)d_ws;
  float* Xb = ws;                        // residual X (S128 f32)
  // ping-pong set 0
  u16*  Q0  = (u16*)(Xb + S128);         // BT*32
  u16*  K0  = Q0 + (size_t)BT*32;        // BT*32
  u16*  Vt0 = K0 + (size_t)BT*32;        // BT*64
  // ping-pong set 1
  u16*  Q1  = Vt0 + (size_t)BT*64;       // BT*32
  u16*  K1  = Q1 + (size_t)BT*32;
  u16*  Vt1 = K1 + (size_t)BT*32;
  u16*  G0  = Vt1 + (size_t)BT*64;       // S256
  u16*  G1  = G0 + S256;                 // S256
  u16*  WtBf = G1 + S256;                // bf16 weights (804864 u16)

  double lgA = log(1.0/32.0), lgB = log(1.0/512.0);
  float4 l2g;
  {
    double g0 = 1.0 - exp(lgA + 0.0*(lgB-lgA)/3.0);
    double g1 = 1.0 - exp(lgA + 1.0*(lgB-lgA)/3.0);
    double g2 = 1.0 - exp(lgA + 2.0*(lgB-lgA)/3.0);
    double g3 = 1.0 - exp(lgA + 3.0*(lgB-lgA)/3.0);
    l2g.x = (float)(log(g0)/log(2.0));
    l2g.y = (float)(log(g1)/log(2.0));
    l2g.z = (float)(log(g2)/log(2.0));
    l2g.w = (float)(log(g3)/log(2.0));
  }

  wconv_kernel<<<3144, 256, 0, stream>>>(wq, wk, wv, wg, wo, ffn_w1, ffn_w2, dec_w1,
                                         rem_w2, rem_w3, WtBf);
  embed_kernel<<<BT/64, 256, 0, stream>>>(x, rem_w1, rem_b1, rem_b2, rem_b3,
                                          WtBf+794624, ln1_w, ln1_b, WtBf,
                                          Xb, Q0, K0, Vt0, G0);

  for(int li=0; li<4; li++){
    u16* Wt_l = WtBf + (size_t)li*196608;
    const float* gnw_l = gn_w + (size_t)li*VDIM;
    const float* gnb_l = gn_b + (size_t)li*VDIM;
    const float* l2w = ln2_w + (size_t)li*HID, *l2b = ln2_b + (size_t)li*HID;
    const float* f1b = ffn_b1 + (size_t)li*FFND;
    const float* f2b = ffn_b2 + (size_t)li*HID;
    int nli = (li+1)&3;
    const float* n1w = ln1_w + (size_t)nli*HID, *n1b = ln1_b + (size_t)nli*HID;
    const u16* Wq_next = (li<3) ? (WtBf + (size_t)(li+1)*196608) : nullptr;

    const u16* Qi  = (li&1) ? Q1  : Q0;
    const u16* Ki  = (li&1) ? K1  : K0;
    const u16* Vti = (li&1) ? Vt1 : Vt0;
    const u16* Gi  = (li&1) ? G1  : G0;
    u16* Qo  = (li&1) ? Q0  : Q1;
    u16* Ko  = (li&1) ? K0  : K1;
    u16* Vto = (li&1) ? Vt0 : Vt1;
    u16* Go  = (li&1) ? G0  : G1;

    layer_kernel<<<BT/64, 512, 0, stream>>>(
        Qi, Ki, Vti, Gi, gnw_l, gnb_l, l2g,
        Wt_l+98304, Wt_l+131072, f1b, Wt_l+163840, f2b,
        Xb, l2w, l2b, n1w, n1b, Xb,
        Wq_next, Qo, Ko, Vto, Go,
        WtBf+786432, dec_b1, dec_w2, dec_b2, outp);
  }
}

// Round 15
// 388.702 us; speedup vs baseline: 1.5490x; 1.0736x over previous
//
#include <hip/hip_runtime.h>
#include <math.h>
#include <cmath>

#define SEQ   512
#define NBATCH 64
#define BT    32768      // 64*512 tokens
#define HID   128
#define NHEAD 4
#define HD    32
#define VHD   64
#define VDIM  256
#define FFND  256

typedef __attribute__((ext_vector_type(8))) short bf16x8;
typedef __attribute__((ext_vector_type(4))) float f32x4;
typedef unsigned short u16;

__device__ __forceinline__ float gelu_f(float x){ return 0.5f*x*(1.f+erff(x*0.70710678118f)); }

// HW bf16 convert (compiler-native __bf16 cast; RTNE)
__device__ __forceinline__ u16 f2bf(float f){
  __bf16 h = (__bf16)f;
  union{__bf16 h; u16 u;} v; v.h = h; return v.u;
}
__device__ __forceinline__ float bf2f(u16 u){
  union{unsigned u; float f;} v; v.u = ((unsigned)u)<<16; return v.f;
}

// async 16B global->LDS (HW scatters lane i at ldsbase + i*16)
__device__ __forceinline__ void gload16(const void* g, void* l){
  __builtin_amdgcn_global_load_lds(
      (const __attribute__((address_space(1))) unsigned*)g,
      (__attribute__((address_space(3))) unsigned*)l, 16, 0, 0);
}

// stage a 128-row x 128-u16 weight tile, XOR-swizzled (phys16 = log16 ^ (row&15))
// B-frag read: logical (row, ks*32+quad*8) -> sW[row*128 + (((ks*4+quad)^(row&15))<<3)]
#define STAGE_TILE_N(dst, base, strideU16, colOffU16, wid_, srow_, phys16l_, NIT) \
  do{                                                                           \
    _Pragma("unroll")                                                           \
    for(int it_=0; it_<NIT; it_++){                                             \
      int blk_ = (wid_)*NIT + it_;                                              \
      int row_ = blk_*4 + (srow_);                                              \
      int log16_ = (phys16l_) ^ (row_&15);                                      \
      gload16((base) + (size_t)row_*(strideU16) + (colOffU16) + log16_*8,       \
              &(dst)[blk_*512]);                                                \
    }                                                                           \
  }while(0)

#define STAGE_TILE(dst, base, strideU16, colOffU16, wid_, srow_, phys16l_) \
  STAGE_TILE_N(dst, base, strideU16, colOffU16, wid_, srow_, phys16l_, 8)

// ---------------- weight convert + transpose -> bf16 Wt[N][K] ----------------
// per-layer region (196608 u16): [0)qkvg 768x128  [98304)wo 128x256  [131072)f1 256x128  [163840)f2 128x256
// tail: 786432 dec_w1t 64x128 (8192); 794624 rem_w2t 64x32 (2048); 796672 rem_w3t 128x64 (8192). total 804864
__global__ __launch_bounds__(256) void wconv_kernel(
    const float* __restrict__ wq, const float* __restrict__ wk,
    const float* __restrict__ wv, const float* __restrict__ wg,
    const float* __restrict__ wo, const float* __restrict__ f1,
    const float* __restrict__ f2, const float* __restrict__ dw1,
    const float* __restrict__ w2e, const float* __restrict__ w3e,
    u16* __restrict__ Wt)
{
  int idx = blockIdx.x*256 + threadIdx.x;   // 0..804863
  if(idx >= 786432){
    int q = idx - 786432;
    if(q < 8192){ int col=q>>7, h=q&127; Wt[idx]=f2bf(dw1[h*64+col]); }
    else if(q < 10240){ int p=q-8192; int row=p>>5, col=p&31; Wt[idx]=f2bf(w2e[col*64+row]); }
    else { int p=q-10240; int row=p>>6, col=p&63; Wt[idx]=f2bf(w3e[col*128+row]); }
    return;
  }
  int layer = idx / 196608;
  int r = idx - layer*196608;
  u16* W = Wt + (size_t)layer*196608;
  const float* wq_l = wq + (size_t)layer*16384;
  const float* wk_l = wk + (size_t)layer*16384;
  const float* wv_l = wv + (size_t)layer*32768;
  const float* wg_l = wg + (size_t)layer*32768;
  const float* wo_l = wo + (size_t)layer*32768;
  const float* f1_l = f1 + (size_t)layer*32768;
  const float* f2_l = f2 + (size_t)layer*32768;
  float v;
  if(r < 98304){
    int col = r>>7, h = r&127;
    if(col<128){ int n=col>>5, d=col&31; v = wq_l[(n*128+h)*32+d]; }
    else if(col<256){ int c=col-128, n=c>>5, d=c&31; v = wk_l[(n*128+h)*32+d]; }
    else if(col<512){ int c=col-256, n=c>>6, j=c&63; v = wv_l[(n*128+h)*64+j]; }
    else { int p=col-512; v = wg_l[h*256+p]; }
    W[r] = f2bf(v);
  } else if(r < 131072){
    int q = r-98304; int col=q>>8, k=q&255;
    W[r] = f2bf(wo_l[k*128+col]);
  } else if(r < 163840){
    int q = r-131072; int col=q>>7, h=q&127;
    W[r] = f2bf(f1_l[h*256+col]);
  } else {
    int q = r-163840; int col=q>>8, k=q&255;
    W[r] = f2bf(f2_l[k*128+col]);
  }
}

// ---------------- qkvg epilogue helper (4-wave version, used by embed_kernel) ----------------
__device__ __forceinline__ void qkvg_epilogue(
    int nc, f32x4 acc[2][4], u16* stg,
    int t, int mrow, int quad, int r0q, int c0q, int b, int l0, int tok0,
    u16* __restrict__ Q, u16* __restrict__ K,
    u16* __restrict__ Vt, u16* __restrict__ G)
{
  if(nc < 2){
    bool isK = (nc==1);
    float sgn = isK ? -1.f : 1.f;
    #pragma unroll
    for(int cc=0;cc<4;cc++){
      int colc = c0q + cc*16 + mrow;
      int i = (colc&31)>>1;
      float log2bs = log2f(((float)i + 12.8f)*(1.f/44.8f));
      float invf   = exp2f(-(float)i * (13.28771238f/16.f));
      float rstep  = exp2f(sgn*log2bs*(1.f/512.f));
      float c1 = cosf(invf), s1 = sinf(invf);
      #pragma unroll
      for(int rr=0;rr<2;rr++){
        int rowl0 = r0q + rr*16 + quad*4;
        float lb = (float)(l0 + rowl0);
        float sc = exp2f(sgn*log2bs*lb*(1.f/512.f));
        float ang = lb*invf;
        float u = cosf(ang)*sc, v = sinf(ang)*sc;
        #pragma unroll
        for(int reg=0;reg<4;reg++){
          int rowl = rowl0 + reg;
          float val = acc[rr][cc][reg];
          float partner = __shfl_xor(val, 1);
          float o = (colc&1) ? (val*u + partner*v) : (val*u - partner*v);
          stg[rowl*136 + colc] = f2bf(o);
          float un = (u*c1 - v*s1)*rstep;
          float vn = (u*s1 + v*c1)*rstep;
          u = un; v = vn;
        }
      }
    }
    __syncthreads();
    u16* O = isK ? K : Q;
    for(int th=t; th<1024; th+=256){
      int row=th>>4, n=(th>>2)&3, seg=th&3;
      *(uint4*)&O[(((size_t)(b*4+n)*512) + (l0+row))*32 + seg*8]
        = *(const uint4*)&stg[row*136 + n*32 + seg*8];
    }
  } else if(nc < 4){
    #pragma unroll
    for(int cc=0;cc<4;cc++){
      int colc = c0q + cc*16 + mrow;
      #pragma unroll
      for(int rr=0;rr<2;rr++){
        #pragma unroll
        for(int reg=0;reg<4;reg++){
          int rowl = r0q + rr*16 + quad*4 + reg;
          stg[colc*72 + rowl] = f2bf(acc[rr][cc][reg]);
        }
      }
    }
    __syncthreads();
    int jbase = (nc-2)*128;
    for(int th=t; th<1024; th+=256){
      int row=th>>3, seg=th&7;
      int jg = jbase + row; int n = jg>>6, j = jg&63;
      *(uint4*)&Vt[(((size_t)(b*4+n)*64) + j)*512 + l0 + seg*8]
        = *(const uint4*)&stg[row*72 + seg*8];
    }
  } else {
    #pragma unroll
    for(int cc=0;cc<4;cc++){
      int colc = c0q + cc*16 + mrow;
      #pragma unroll
      for(int rr=0;rr<2;rr++){
        #pragma unroll
        for(int reg=0;reg<4;reg++){
          int rowl = r0q + rr*16 + quad*4 + reg;
          stg[rowl*136 + colc] = f2bf(acc[rr][cc][reg]);
        }
      }
    }
    __syncthreads();
    int gc0 = (nc-4)*128;
    for(int th=t; th<1024; th+=256){
      int row=th>>4, seg=th&15;
      *(uint4*)&G[((size_t)(tok0+row))*256 + gc0 + seg*8]
        = *(const uint4*)&stg[row*136 + seg*8];
    }
  }
}

// ---------------- embed (MFMA) + layer-0 LN1 + FUSED layer-0 qkvg ----------------
// xn never leaves LDS: big[0..8704) holds xn (stride 136); weight chunks stage into
// big[8704..25088); epilogue staging tops out at 8704+9216=17920. All disjoint.
__global__ __launch_bounds__(256) void embed_kernel(
    const float* __restrict__ x,
    const float* __restrict__ w1, const float* __restrict__ b1,
    const float* __restrict__ b2, const float* __restrict__ b3,
    const u16* __restrict__ W23t,     // w2t[64][32] at 0, w3t[128][64] at 2048
    const float* __restrict__ lnw, const float* __restrict__ lnb,
    const u16* __restrict__ Wt,       // layer-0 qkvg weights (6 x 16384)
    float* __restrict__ X,
    u16* __restrict__ Q, u16* __restrict__ K,
    u16* __restrict__ Vt, u16* __restrict__ G)
{
  __shared__ float sx[64][6];
  __shared__ float sw1[160], sb1[32], sb2[64], sb3[128];
  __shared__ u16 big[25088];
  int t=threadIdx.x, lane=t&63, wid=t>>6, mrow=lane&15, quad=lane>>4, r0=wid*16;
  int tok0=blockIdx.x*64;

  for(int i=t;i<320;i+=256) sx[i/5][i%5]=x[(size_t)tok0*5+i];
  for(int i=t;i<160;i+=256) sw1[i]=w1[i];
  if(t<32) sb1[t]=b1[t];
  if(t<64) sb2[t]=b2[t];
  if(t<128) sb3[t]=b3[t];
  for(int c=t;c<256;c+=256){ int row=c>>2, c8=(c&3)*8;
    *(uint4*)&big[2560+row*40+c8]=*(const uint4*)&W23t[row*32+c8]; }
  for(int c=t;c<1024;c+=256){ int row=c>>3, c8=(c&7)*8;
    *(uint4*)&big[9728+row*72+c8]=*(const uint4*)&W23t[2048+row*64+c8]; }
  __syncthreads();

  for(int task=t; task<2048; task+=256){
    int tok=task>>5, j=task&31;
    float a=sb1[j];
    #pragma unroll
    for(int i=0;i<5;i++) a+=sx[tok][i]*sw1[i*32+j];
    big[tok*40+j]=f2bf(gelu_f(a));
  }
  __syncthreads();

  f32x4 h2[4];
  #pragma unroll
  for(int cc=0;cc<4;cc++) h2[cc]=(f32x4){0.f,0.f,0.f,0.f};
  {
    bf16x8 a=*(const bf16x8*)&big[(r0+mrow)*40+quad*8];
    #pragma unroll
    for(int cc=0;cc<4;cc++){
      bf16x8 b=*(const bf16x8*)&big[2560+(cc*16+mrow)*40+quad*8];
      h2[cc]=__builtin_amdgcn_mfma_f32_16x16x32_bf16(a,b,h2[cc],0,0,0);
    }
  }
  #pragma unroll
  for(int cc=0;cc<4;cc++){
    float bs=sb2[cc*16+mrow];
    #pragma unroll
    for(int reg=0;reg<4;reg++)
      big[5120+(r0+quad*4+reg)*72+cc*16+mrow]=f2bf(gelu_f(h2[cc][reg]+bs));
  }
  __syncthreads();

  f32x4 xac[8];
  #pragma unroll
  for(int cc=0;cc<8;cc++) xac[cc]=(f32x4){0.f,0.f,0.f,0.f};
  #pragma unroll
  for(int ks=0;ks<2;ks++){
    bf16x8 a=*(const bf16x8*)&big[5120+(r0+mrow)*72+ks*32+quad*8];
    #pragma unroll
    for(int cc=0;cc<8;cc++){
      bf16x8 b=*(const bf16x8*)&big[9728+(cc*16+mrow)*72+ks*32+quad*8];
      xac[cc]=__builtin_amdgcn_mfma_f32_16x16x32_bf16(a,b,xac[cc],0,0,0);
    }
  }
  __syncthreads();

  #pragma unroll
  for(int reg=0;reg<4;reg++){
    int rowl=r0+quad*4+reg, rowg=tok0+rowl;
    float xv[8], s=0.f, sq=0.f;
    #pragma unroll
    for(int cc=0;cc<8;cc++){
      float v=gelu_f(xac[cc][reg]+sb3[cc*16+mrow]);
      xv[cc]=v; s+=v; sq+=v*v;
    }
    #pragma unroll
    for(int m=1;m<16;m<<=1){ s+=__shfl_xor(s,m); sq+=__shfl_xor(sq,m); }
    float mu=s*(1.f/128.f);
    float var=sq*(1.f/128.f)-mu*mu;
    float rstd=rsqrtf(var+1e-5f);
    #pragma unroll
    for(int cc=0;cc<8;cc++){
      int col=cc*16+mrow;
      X[(size_t)rowg*128+col]=xv[cc];
      big[rowl*136+col]=f2bf((xv[cc]-mu)*rstd*lnw[col]+lnb[col]);
    }
  }
  __syncthreads();

  // ---- fused layer-0 qkvg: A-frags from xn in LDS; 6 chunks via big[8704..]
  u16* sW = big + 8704;
  u16* stg = sW;
  int srow = lane>>4, phys16l = lane&15;
  int r0q = (wid>>1)*32, c0q = (wid&1)*64;
  int b = tok0>>9, l0 = tok0&511;

  bf16x8 a0f[4], a1f[4];
  #pragma unroll
  for(int ks=0; ks<4; ks++){
    a0f[ks] = *(const bf16x8*)&big[(r0q+mrow)*136 + ks*32+quad*8];
    a1f[ks] = *(const bf16x8*)&big[(r0q+16+mrow)*136 + ks*32+quad*8];
  }
  __syncthreads();   // a-frag reads done (xn region stays intact anyway)

  for(int nc=0; nc<6; nc++){
    if(nc) __syncthreads();
    STAGE_TILE(sW, Wt + (size_t)nc*16384, 128, 0, wid, srow, phys16l);
    __syncthreads();

    f32x4 acc[2][4];
    #pragma unroll
    for(int rr=0;rr<2;rr++)
      #pragma unroll
      for(int cc=0;cc<4;cc++) acc[rr][cc] = (f32x4){0.f,0.f,0.f,0.f};
    #pragma unroll
    for(int ks=0; ks<4; ks++){
      #pragma unroll
      for(int cc=0; cc<4; cc++){
        bf16x8 bb = *(const bf16x8*)&sW[(c0q+cc*16+mrow)*128 + (((ks*4+quad)^mrow)<<3)];
        acc[0][cc] = __builtin_amdgcn_mfma_f32_16x16x32_bf16(a0f[ks],bb,acc[0][cc],0,0,0);
        acc[1][cc] = __builtin_amdgcn_mfma_f32_16x16x32_bf16(a1f[ks],bb,acc[1][cc],0,0,0);
      }
    }
    __syncthreads();
    qkvg_epilogue(nc, acc, stg, t, mrow, quad, r0q, c0q, b, l0, tok0, Q, K, Vt, G);
  }
}

// ---------------- qkvg epilogue helper (8-wave version, used by layer_kernel) ----------------
__device__ __forceinline__ void qkvg_epi8(
    int nc, f32x4 acc[4], u16* stg,
    int t, int mrow, int quad, int r0, int c0, int b, int l0, int tok0,
    u16* __restrict__ Q, u16* __restrict__ K,
    u16* __restrict__ Vt, u16* __restrict__ G)
{
  if(nc < 2){
    bool isK = (nc==1);
    float sgn = isK ? -1.f : 1.f;
    #pragma unroll
    for(int cc=0;cc<4;cc++){
      int colc = c0 + cc*16 + mrow;
      int i = (colc&31)>>1;
      float log2bs = log2f(((float)i + 12.8f)*(1.f/44.8f));
      float invf   = exp2f(-(float)i * (13.28771238f/16.f));
      float rstep  = exp2f(sgn*log2bs*(1.f/512.f));
      float c1 = cosf(invf), s1 = sinf(invf);
      int rowl0 = r0 + quad*4;
      float lb = (float)(l0 + rowl0);
      float sc = exp2f(sgn*log2bs*lb*(1.f/512.f));
      float ang = lb*invf;
      float u = cosf(ang)*sc, v = sinf(ang)*sc;
      #pragma unroll
      for(int reg=0;reg<4;reg++){
        int rowl = rowl0 + reg;
        float val = acc[cc][reg];
        float partner = __shfl_xor(val, 1);
        float o = (colc&1) ? (val*u + partner*v) : (val*u - partner*v);
        stg[rowl*136 + colc] = f2bf(o);
        float un = (u*c1 - v*s1)*rstep;
        float vn = (u*s1 + v*c1)*rstep;
        u = un; v = vn;
      }
    }
    __syncthreads();
    u16* O = isK ? K : Q;
    for(int th=t; th<1024; th+=512){
      int row=th>>4, n=(th>>2)&3, seg=th&3;
      *(uint4*)&O[(((size_t)(b*4+n)*512) + (l0+row))*32 + seg*8]
        = *(const uint4*)&stg[row*136 + n*32 + seg*8];
    }
  } else if(nc < 4){
    #pragma unroll
    for(int cc=0;cc<4;cc++){
      int colc = c0 + cc*16 + mrow;
      #pragma unroll
      for(int reg=0;reg<4;reg++){
        int rowl = r0 + quad*4 + reg;
        stg[colc*72 + rowl] = f2bf(acc[cc][reg]);
      }
    }
    __syncthreads();
    int jbase = (nc-2)*128;
    for(int th=t; th<1024; th+=512){
      int row=th>>3, seg=th&7;
      int jg = jbase + row; int n = jg>>6, j = jg&63;
      *(uint4*)&Vt[(((size_t)(b*4+n)*64) + j)*512 + l0 + seg*8]
        = *(const uint4*)&stg[row*72 + seg*8];
    }
  } else {
    #pragma unroll
    for(int cc=0;cc<4;cc++){
      int colc = c0 + cc*16 + mrow;
      #pragma unroll
      for(int reg=0;reg<4;reg++){
        int rowl = r0 + quad*4 + reg;
        stg[rowl*136 + colc] = f2bf(acc[cc][reg]);
      }
    }
    __syncthreads();
    int gc0 = (nc-4)*128;
    for(int th=t; th<1024; th+=512){
      int row=th>>4, seg=th&15;
      *(uint4*)&G[((size_t)(tok0+row))*256 + gc0 + seg*8]
        = *(const uint4*)&stg[row*136 + seg*8];
    }
  }
}

// ---------------- fused LAYER kernel: retention (4 heads) + MLP + qkvg(next) / dec(last) ----------------
// Ret LDS strides at round-11-proven 40/72 (16B-aligned rows for b128; the
// round-12 padding to 44/76 broke ds_*_b128 alignment and regressed 1.7x).
__global__ __launch_bounds__(512, 4) void layer_kernel(
    const u16* __restrict__ Qin, const u16* __restrict__ Kin,
    const u16* __restrict__ Vtin, const u16* __restrict__ Gin,
    const float* __restrict__ gnw, const float* __restrict__ gnb, float4 l2g,
    const u16* __restrict__ Wo,
    const u16* __restrict__ W1t, const float* __restrict__ b1,
    const u16* __restrict__ W2t, const float* __restrict__ b2,
    const float* __restrict__ Xin,
    const float* __restrict__ ln2w, const float* __restrict__ ln2b,
    const float* __restrict__ ln1w, const float* __restrict__ ln1b,
    float* __restrict__ Xout,
    const u16* __restrict__ Wq,   // next layer qkvg weights (nullptr on last layer)
    u16* __restrict__ Qo, u16* __restrict__ Ko,
    u16* __restrict__ Vto, u16* __restrict__ Go,
    const u16* __restrict__ DecW1, const float* __restrict__ db1,
    const float* __restrict__ dw2, const float* __restrict__ db2,
    float* __restrict__ outp)
{
  __shared__ u16 smem[33280];      // bufA[16384] bufB[16384] sRed[512 u16 = 256 f32]
  u16* bufA = smem;
  u16* bufB = smem + 16384;
  float (*sRed)[2][2] = (float(*)[2][2])(smem + 32768);
  int t=threadIdx.x, lane=t&63, wid=t>>6, mrow=lane&15, quad=lane>>4;
  int rg=wid>>1, half=wid&1;
  int r0=rg*16, c0=half*64;
  // complementary-lt block swizzle (round-10 win; bijective over (b,lt))
  int bix = blockIdx.x;
  int kk = (bix>>6)&3, hib = bix>>8;
  int ltsw = hib ? (7-kk) : kk;
  int tok0 = (((bix&63)<<3) | ltsw) * 64;
  int srow = lane>>4, phys16l = lane&15;

  // ================= Phase R: retention, 2 head-pairs =================
  int half8 = wid>>2, lw = wid&3;     // half-block id, local wave in half
  int tl = t & 255;                   // local thread id in half
  int r0l = lw*16;
  int lt = (tok0>>6)&7;               // lt tile index within sequence
  int bq = tok0>>9;                   // batch index
  bf16x8 gfrag[8];

  #pragma unroll
  for(int p=0;p<2;p++){
    int n = 2*p + half8;
    int bn = bq*4 + n;
    float lg2g = (n==0)?l2g.x:(n==1)?l2g.y:(n==2)?l2g.z:l2g.w;
    u16* rK = smem + half8*11776;     // [64] stride 40
    u16* rV = rK + 2560;              // [64] stride 72
    u16* rS = rK + 7168;              // [64] stride 72

    bf16x8 qa = *(const bf16x8*)&Qin[((size_t)bn*512 + lt*64 + r0l+mrow)*32 + quad*8];
    f32x4 oacc[4];
    #pragma unroll
    for(int cc=0;cc<4;cc++) oacc[cc] = (f32x4){0.f,0.f,0.f,0.f};
    float gp1 = exp2f(lg2g), gp2 = gp1*gp1, gp3 = gp2*gp1;
    float gpow[4] = {1.f, gp1, gp2, gp3};
    float gw[4], gb[4];
    #pragma unroll
    for(int cc=0;cc<4;cc++){ gw[cc]=gnw[n*64+cc*16+mrow]; gb[cc]=gnb[n*64+cc*16+mrow]; }
    int rowl0 = lt*64 + r0l + quad*4;

    // T14 load-hoist: tile mt+1 in regs while tile mt computes
    int krow = tl>>2, kc8 = (tl&3)*8;
    int vrow = tl>>3, vc8 = (tl&7)*8;
    const u16* Kb = Kin  + ((size_t)bn*512 + krow)*32 + kc8;
    const u16* V0 = Vtin + ((size_t)bn*64 + vrow)*512 + vc8;
    const u16* V1 = Vtin + ((size_t)bn*64 + vrow+32)*512 + vc8;
    uint4 ldk  = *(const uint4*)(Kb);
    uint4 ldv0 = *(const uint4*)(V0);
    uint4 ldv1 = *(const uint4*)(V1);

    for(int mt=0; mt<=lt; mt++){
      if(mt) __syncthreads();
      *(uint4*)&rK[krow*40+kc8]      = ldk;
      *(uint4*)&rV[vrow*72+vc8]      = ldv0;
      *(uint4*)&rV[(vrow+32)*72+vc8] = ldv1;
      if(mt < lt){
        ldk  = *(const uint4*)(Kb + (size_t)(mt+1)*2048);
        ldv0 = *(const uint4*)(V0 + (mt+1)*64);
        ldv1 = *(const uint4*)(V1 + (mt+1)*64);
      }
      __syncthreads();
      f32x4 sacc[4];
      #pragma unroll
      for(int cc=0;cc<4;cc++){
        bf16x8 bb = *(const bf16x8*)&rK[(cc*16+mrow)*40 + quad*8];
        sacc[cc] = __builtin_amdgcn_mfma_f32_16x16x32_bf16(qa,bb,(f32x4){0.f,0.f,0.f,0.f},0,0,0);
      }
      #pragma unroll
      for(int cc=0;cc<4;cc++){
        int colm = mt*64 + cc*16 + mrow;
        int d0 = rowl0 - colm;
        float w0 = exp2f(lg2g*(float)d0);
        #pragma unroll
        for(int reg=0;reg<4;reg++){
          float w = (d0+reg>=0) ? w0*gpow[reg] : 0.f;
          rS[(r0l+quad*4+reg)*72 + cc*16+mrow] = f2bf(sacc[cc][reg]*w);
        }
      }
      __syncthreads();
      #pragma unroll
      for(int ks=0;ks<2;ks++){
        bf16x8 a = *(const bf16x8*)&rS[(r0l+mrow)*72 + ks*32+quad*8];
        #pragma unroll
        for(int cc=0;cc<4;cc++){
          bf16x8 bb = *(const bf16x8*)&rV[(cc*16+mrow)*72 + ks*32+quad*8];
          oacc[cc] = __builtin_amdgcn_mfma_f32_16x16x32_bf16(a,bb,oacc[cc],0,0,0);
        }
      }
    }

    __syncthreads();
    // GroupNorm + silu(G) gate -> gated values into rS (stride 72, v-dim cols 0..63)
    #pragma unroll
    for(int reg=0;reg<4;reg++){
      float s=0.f, sq=0.f;
      #pragma unroll
      for(int cc=0;cc<4;cc++){ float v=oacc[cc][reg]; s+=v; sq+=v*v; }
      #pragma unroll
      for(int m=1;m<16;m<<=1){ s+=__shfl_xor(s,m); sq+=__shfl_xor(sq,m); }
      float mu = s*(1.f/64.f);
      float var = sq*(1.f/64.f) - mu*mu;
      float rn = rsqrtf(var + 1e-5f);
      int rowl = r0l + quad*4 + reg;
      int l = lt*64 + rowl;
      size_t gbase = ((size_t)(bq*512 + l))*256 + n*64;
      #pragma unroll
      for(int cc=0;cc<4;cc++){
        float gg = bf2f(Gin[gbase + cc*16+mrow]);
        float gate = gg/(1.f+expf(-gg));
        rS[rowl*72 + cc*16+mrow] = f2bf(gate*((oacc[cc][reg]-mu)*rn*gw[cc] + gb[cc]));
      }
    }
    __syncthreads();
    // gfrag extraction for BOTH heads of this pair (head nn -> gfrag[2nn..2nn+1])
    #pragma unroll
    for(int hh=0; hh<2; hh++){
      int nn = 2*p + hh;
      const u16* src = smem + hh*11776 + 7168;
      #pragma unroll
      for(int ksl=0; ksl<2; ksl++)
        gfrag[2*nn+ksl] = *(const bf16x8*)&src[(r0+mrow)*72 + ksl*32 + quad*8];
    }
    __syncthreads();   // reads done before next pair / STAGE overwrites
  }

  // ================= Phase M: MLP (round-8-proven body) =================
  STAGE_TILE_N(bufA, Wo, 256, 0, wid, srow, phys16l, 4);
  __syncthreads();                               // bufA(wo-kh0) ready

  // ---- P1: wo kh0 (read bufA) | stage wo kh1 -> bufB
  STAGE_TILE_N(bufB, Wo, 256, 128, wid, srow, phys16l, 4);
  f32x4 yac[4];
  #pragma unroll
  for(int cc=0;cc<4;cc++) yac[cc]=(f32x4){0.f,0.f,0.f,0.f};
  #pragma unroll
  for(int cc=0;cc<4;cc++){
    #pragma unroll
    for(int ks=0;ks<4;ks++){
      bf16x8 b=*(const bf16x8*)&bufA[(c0+cc*16+mrow)*128 + (((ks*4+quad)^mrow)<<3)];
      yac[cc]=__builtin_amdgcn_mfma_f32_16x16x32_bf16(gfrag[ks],b,yac[cc],0,0,0);
    }
  }
  __syncthreads();                               // bufA reads done; bufB drained

  // ---- P2: wo kh1 (read bufB) | stage ffn1-nh0 -> bufA ; LN2 partials
  STAGE_TILE_N(bufA, W1t, 128, 0, wid, srow, phys16l, 4);
  #pragma unroll
  for(int cc=0;cc<4;cc++){
    #pragma unroll
    for(int ks=0;ks<4;ks++){
      bf16x8 b=*(const bf16x8*)&bufB[(c0+cc*16+mrow)*128 + (((ks*4+quad)^mrow)<<3)];
      yac[cc]=__builtin_amdgcn_mfma_f32_16x16x32_bf16(gfrag[4+ks],b,yac[cc],0,0,0);
    }
  }
  float yv[4][4];
  #pragma unroll
  for(int reg=0;reg<4;reg++){
    int rowl=r0+quad*4+reg, rowg=tok0+rowl;
    float s=0.f, sq=0.f;
    #pragma unroll
    for(int cc=0;cc<4;cc++){
      float v=yac[cc][reg]+Xin[(size_t)rowg*128+c0+cc*16+mrow];
      yv[cc][reg]=v; s+=v; sq+=v*v;
    }
    #pragma unroll
    for(int m=1;m<16;m<<=1){ s+=__shfl_xor(s,m); sq+=__shfl_xor(sq,m); }
    if(mrow==0){ sRed[rowl][half][0]=s; sRed[rowl][half][1]=sq; }
  }
  __syncthreads();                               // bufB reads done; sRed ready; bufA drained

  // ---- LN2 finish: Z -> bufB (dead; stride 136)
  #pragma unroll
  for(int reg=0;reg<4;reg++){
    int rowl=r0+quad*4+reg;
    float s =sRed[rowl][0][0]+sRed[rowl][1][0];
    float sq=sRed[rowl][0][1]+sRed[rowl][1][1];
    float mu=s*(1.f/128.f);
    float var=sq*(1.f/128.f)-mu*mu;
    float rstd=rsqrtf(var+1e-5f);
    #pragma unroll
    for(int cc=0;cc<4;cc++){
      int col=c0+cc*16+mrow;
      bufB[rowl*136+col]=f2bf((yv[cc][reg]-mu)*rstd*ln2w[col]+ln2b[col]);
    }
  }
  __syncthreads();
  bf16x8 az[4];
  #pragma unroll
  for(int ks=0;ks<4;ks++) az[ks]=*(const bf16x8*)&bufB[(r0+mrow)*136+ks*32+quad*8];
  __syncthreads();                               // az reads done -> bufB stageable

  // ---- P3: ffn1 nh0 (read bufA) | stage ffn1-nh1 -> bufB ; H0 via dead bufA
  bf16x8 hfrag[8];
  STAGE_TILE_N(bufB, W1t + (size_t)16384, 128, 0, wid, srow, phys16l, 4);
  {
    f32x4 hac[4];
    #pragma unroll
    for(int cc=0;cc<4;cc++) hac[cc]=(f32x4){0.f,0.f,0.f,0.f};
    #pragma unroll
    for(int cc=0;cc<4;cc++){
      #pragma unroll
      for(int ks=0;ks<4;ks++){
        bf16x8 b=*(const bf16x8*)&bufA[(c0+cc*16+mrow)*128 + (((ks*4+quad)^mrow)<<3)];
        hac[cc]=__builtin_amdgcn_mfma_f32_16x16x32_bf16(az[ks],b,hac[cc],0,0,0);
      }
    }
    __syncthreads();                             // bufA reads done; bufB drained
    #pragma unroll
    for(int cc=0;cc<4;cc++){
      float bs=b1[c0+cc*16+mrow];
      #pragma unroll
      for(int reg=0;reg<4;reg++)
        bufA[(r0+quad*4+reg)*136 + c0+cc*16+mrow]=f2bf(gelu_f(hac[cc][reg]+bs));
    }
    __syncthreads();
    #pragma unroll
    for(int ks=0;ks<4;ks++) hfrag[ks]=*(const bf16x8*)&bufA[(r0+mrow)*136+ks*32+quad*8];
    __syncthreads();                             // hfrag0 reads done -> bufA stageable
  }

  // ---- P4: ffn1 nh1 (read bufB) | stage ffn2-kh0 -> bufA ; H1 via dead bufB
  STAGE_TILE_N(bufA, W2t, 256, 0, wid, srow, phys16l, 4);
  {
    f32x4 hac[4];
    #pragma unroll
    for(int cc=0;cc<4;cc++) hac[cc]=(f32x4){0.f,0.f,0.f,0.f};
    #pragma unroll
    for(int cc=0;cc<4;cc++){
      #pragma unroll
      for(int ks=0;ks<4;ks++){
        bf16x8 b=*(const bf16x8*)&bufB[(c0+cc*16+mrow)*128 + (((ks*4+quad)^mrow)<<3)];
        hac[cc]=__builtin_amdgcn_mfma_f32_16x16x32_bf16(az[ks],b,hac[cc],0,0,0);
      }
    }
    __syncthreads();                             // bufB reads done; bufA drained
    #pragma unroll
    for(int cc=0;cc<4;cc++){
      float bs=b1[128+c0+cc*16+mrow];
      #pragma unroll
      for(int reg=0;reg<4;reg++)
        bufB[(r0+quad*4+reg)*136 + c0+cc*16+mrow]=f2bf(gelu_f(hac[cc][reg]+bs));
    }
    __syncthreads();
    #pragma unroll
    for(int ks=0;ks<4;ks++) hfrag[4+ks]=*(const bf16x8*)&bufB[(r0+mrow)*136+ks*32+quad*8];
    __syncthreads();                             // hfrag1 reads done -> bufB stageable
  }

  // ---- P5: ffn2 kh0 (read bufA) | stage ffn2-kh1 -> bufB
  STAGE_TILE_N(bufB, W2t, 256, 128, wid, srow, phys16l, 4);
  f32x4 xac[4];
  #pragma unroll
  for(int cc=0;cc<4;cc++) xac[cc]=(f32x4){0.f,0.f,0.f,0.f};
  #pragma unroll
  for(int cc=0;cc<4;cc++){
    #pragma unroll
    for(int ks=0;ks<4;ks++){
      bf16x8 b=*(const bf16x8*)&bufA[(c0+cc*16+mrow)*128 + (((ks*4+quad)^mrow)<<3)];
      xac[cc]=__builtin_amdgcn_mfma_f32_16x16x32_bf16(hfrag[ks],b,xac[cc],0,0,0);
    }
  }
  __syncthreads();                               // bufA reads done; bufB drained

  // ---- P6: ffn2 kh1 (read bufB) | stage qkvg-nc0 -> bufA ; epilogue partials
  if(Wq) STAGE_TILE_N(bufA, Wq, 128, 0, wid, srow, phys16l, 4);
  #pragma unroll
  for(int cc=0;cc<4;cc++){
    #pragma unroll
    for(int ks=0;ks<4;ks++){
      bf16x8 b=*(const bf16x8*)&bufB[(c0+cc*16+mrow)*128 + (((ks*4+quad)^mrow)<<3)];
      xac[cc]=__builtin_amdgcn_mfma_f32_16x16x32_bf16(hfrag[4+ks],b,xac[cc],0,0,0);
    }
  }
  float xv[4][4];
  #pragma unroll
  for(int reg=0;reg<4;reg++){
    int rowl=r0+quad*4+reg;
    float s=0.f, sq=0.f;
    #pragma unroll
    for(int cc=0;cc<4;cc++){
      float v=xac[cc][reg]+b2[c0+cc*16+mrow]+yv[cc][reg];
      xv[cc][reg]=v; s+=v; sq+=v*v;
    }
    #pragma unroll
    for(int m=1;m<16;m<<=1){ s+=__shfl_xor(s,m); sq+=__shfl_xor(sq,m); }
    if(mrow==0){ sRed[rowl][half][0]=s; sRed[rowl][half][1]=sq; }
  }
  __syncthreads();                               // bufB reads done; sRed ready; bufA drained

  if(Wq){
    // ---- epilogue: Xout stores; LN1(next) -> xn in dead bufB
    #pragma unroll
    for(int reg=0;reg<4;reg++){
      int rowl=r0+quad*4+reg, rowg=tok0+rowl;
      float s =sRed[rowl][0][0]+sRed[rowl][1][0];
      float sq=sRed[rowl][0][1]+sRed[rowl][1][1];
      float mu=s*(1.f/128.f);
      float var=sq*(1.f/128.f)-mu*mu;
      float rstd=rsqrtf(var+1e-5f);
      #pragma unroll
      for(int cc=0;cc<4;cc++){
        int col=c0+cc*16+mrow;
        Xout[(size_t)rowg*128+col]=xv[cc][reg];
        bufB[rowl*136+col]=f2bf((xv[cc][reg]-mu)*rstd*ln1w[col]+ln1b[col]);
      }
    }
    __syncthreads();
    bf16x8 aq[4];
    #pragma unroll
    for(int ks=0; ks<4; ks++)
      aq[ks] = *(const bf16x8*)&bufB[(r0+mrow)*136 + ks*32+quad*8];
    __syncthreads();                             // aq reads done -> bufB stageable

    // ---- fused qkvg: nc reads buf(nc&1); stage nc+1 into the other; epi reuses dead buf
    int b = tok0>>9, l0 = tok0&511;
    for(int nc=0; nc<6; nc++){
      u16* cur = (nc&1) ? bufB : bufA;
      u16* nxt = (nc&1) ? bufA : bufB;
      if(nc<5) STAGE_TILE_N(nxt, Wq + (size_t)(nc+1)*16384, 128, 0, wid, srow, phys16l, 4);

      f32x4 acc[4];
      #pragma unroll
      for(int cc=0;cc<4;cc++) acc[cc] = (f32x4){0.f,0.f,0.f,0.f};
      #pragma unroll
      for(int ks=0; ks<4; ks++){
        #pragma unroll
        for(int cc=0; cc<4; cc++){
          bf16x8 bb = *(const bf16x8*)&cur[(c0+cc*16+mrow)*128 + (((ks*4+quad)^mrow)<<3)];
          acc[cc] = __builtin_amdgcn_mfma_f32_16x16x32_bf16(aq[ks],bb,acc[cc],0,0,0);
        }
      }
      __syncthreads();                           // cur reads done; nxt drained
      qkvg_epi8(nc, acc, cur, t, mrow, quad, r0, c0, b, l0, tok0, Qo, Ko, Vto, Go);
      __syncthreads();                           // epi's stg(cur) reads done -> cur stageable
    }
    return;
  }

  // ================= Last layer: fused DECODER (512 threads) =================
  u16*  sWd  = smem;
  float* sHd = (float*)(smem + 8704);
  float* sw2s= (float*)(smem + 17408);
  float* sLs = (float*)(smem + 19968);
  float* sb2s= (float*)(smem + 22528);
  u16*  sXd  = smem + 24064;

  // X bf16 -> sXd (own rows/cols from regs; no Xout HBM write on last layer)
  #pragma unroll
  for(int reg=0;reg<4;reg++){
    int rowl=r0+quad*4+reg;
    #pragma unroll
    for(int cc=0;cc<4;cc++){
      int col=c0+cc*16+mrow;
      sXd[rowl*136+col]=f2bf(xv[cc][reg]);
    }
  }
  // stage dec_w1t [64][128] -> sWd stride 136 ; sw2/sb2
  for(int th=t; th<1024; th+=512){
    int row=th>>4, c8=(th&15)*8;
    *(uint4*)&sWd[row*136+c8] = *(const uint4*)&DecW1[(size_t)row*128 + c8];
  }
  for(int i=t;i<1280;i+=512) sw2s[i]=dw2[i];
  if(t<20) sb2s[t]=db2[t];
  __syncthreads();

  // MFMA: wave (rg,half): rows r0..r0+15, cols half*32 + cc*16, cc in {0,1}; K=128
  {
    f32x4 dacc[2];
    #pragma unroll
    for(int cc=0;cc<2;cc++) dacc[cc]=(f32x4){0.f,0.f,0.f,0.f};
    #pragma unroll
    for(int ks=0; ks<4; ks++){
      int koff = ks*32 + quad*8;
      bf16x8 a = *(const bf16x8*)&sXd[(r0+mrow)*136 + koff];
      #pragma unroll
      for(int cc=0; cc<2; cc++){
        bf16x8 b = *(const bf16x8*)&sWd[(half*32+cc*16+mrow)*136 + koff];
        dacc[cc] = __builtin_amdgcn_mfma_f32_16x16x32_bf16(a,b,dacc[cc],0,0,0);
      }
    }
    #pragma unroll
    for(int cc=0;cc<2;cc++){
      int col = half*32 + cc*16 + mrow;
      float bb = db1[col];
      #pragma unroll
      for(int reg=0;reg<4;reg++)
        sHd[(r0+quad*4+reg)*68 + col] = gelu_f(dacc[cc][reg] + bb);
    }
  }
  __syncthreads();

  for(int task=t; task<1280; task+=512){
    int tk = task/20, o = task - tk*20;
    float a = sb2s[o];
    for(int k=0;k<64;k++) a += sHd[tk*68+k]*sw2s[k*20+o];
    sLs[tk*20+o] = a;
  }
  __syncthreads();
  if(t < 64){
    float mx = -1e30f;
    #pragma unroll
    for(int o=0;o<20;o++) mx = fmaxf(mx, sLs[t*20+o]);
    float sum = 0.f;
    float e[20];
    #pragma unroll
    for(int o=0;o<20;o++){ e[o]=expf(sLs[t*20+o]-mx); sum += e[o]; }
    float inv = 1.f/sum;
    #pragma unroll
    for(int o=0;o<20;o++) sLs[t*20+o] = e[o]*inv;
  }
  __syncthreads();
  for(int th=t; th<1280; th+=512){
    outp[(size_t)tok0*20 + th] = sLs[th];
  }
}

extern "C" void kernel_launch(void* const* d_in, const int* in_sizes, int n_in,
                              void* d_out, int out_size, void* d_ws, size_t ws_size,
                              hipStream_t stream) {
  (void)in_sizes; (void)n_in; (void)out_size; (void)ws_size;
  const float* x      = (const float*)d_in[0];
  const float* rem_w1 = (const float*)d_in[1];
  const float* rem_b1 = (const float*)d_in[2];
  const float* rem_w2 = (const float*)d_in[3];
  const float* rem_b2 = (const float*)d_in[4];
  const float* rem_w3 = (const float*)d_in[5];
  const float* rem_b3 = (const float*)d_in[6];
  const float* wq     = (const float*)d_in[7];
  const float* wk     = (const float*)d_in[8];
  const float* wv     = (const float*)d_in[9];
  const float* wg     = (const float*)d_in[10];
  const float* wo     = (const float*)d_in[11];
  const float* gn_w   = (const float*)d_in[12];
  const float* gn_b   = (const float*)d_in[13];
  const float* ln1_w  = (const float*)d_in[14];
  const float* ln1_b  = (const float*)d_in[15];
  const float* ln2_w  = (const float*)d_in[16];
  const float* ln2_b  = (const float*)d_in[17];
  const float* ffn_w1 = (const float*)d_in[18];
  const float* ffn_b1 = (const float*)d_in[19];
  const float* ffn_w2 = (const float*)d_in[20];
  const float* ffn_b2 = (const float*)d_in[21];
  const float* dec_w1 = (const float*)d_in[22];
  const float* dec_b1 = (const float*)d_in[23];
  const float* dec_w2 = (const float*)d_in[24];
  const float* dec_b2 = (const float*)d_in[25];
  float* outp = (float*)d_out;

  const size_t S128 = (size_t)BT*128;
  const size_t S256 = (size_t)BT*256;
  float* ws = (float*)d_ws;
  float* Xb = ws;                        // residual X (S128 f32)
  // ping-pong set 0
  u16*  Q0  = (u16*)(Xb + S128);         // BT*32
  u16*  K0  = Q0 + (size_t)BT*32;        // BT*32
  u16*  Vt0 = K0 + (size_t)BT*32;        // BT*64
  // ping-pong set 1
  u16*  Q1  = Vt0 + (size_t)BT*64;       // BT*32
  u16*  K1  = Q1 + (size_t)BT*32;
  u16*  Vt1 = K1 + (size_t)BT*32;
  u16*  G0  = Vt1 + (size_t)BT*64;       // S256
  u16*  G1  = G0 + S256;                 // S256
  u16*  WtBf = G1 + S256;                // bf16 weights (804864 u16)

  double lgA = log(1.0/32.0), lgB = log(1.0/512.0);
  float4 l2g;
  {
    double g0 = 1.0 - exp(lgA + 0.0*(lgB-lgA)/3.0);
    double g1 = 1.0 - exp(lgA + 1.0*(lgB-lgA)/3.0);
    double g2 = 1.0 - exp(lgA + 2.0*(lgB-lgA)/3.0);
    double g3 = 1.0 - exp(lgA + 3.0*(lgB-lgA)/3.0);
    l2g.x = (float)(log(g0)/log(2.0));
    l2g.y = (float)(log(g1)/log(2.0));
    l2g.z = (float)(log(g2)/log(2.0));
    l2g.w = (float)(log(g3)/log(2.0));
  }

  wconv_kernel<<<3144, 256, 0, stream>>>(wq, wk, wv, wg, wo, ffn_w1, ffn_w2, dec_w1,
                                         rem_w2, rem_w3, WtBf);
  embed_kernel<<<BT/64, 256, 0, stream>>>(x, rem_w1, rem_b1, rem_b2, rem_b3,
                                          WtBf+794624, ln1_w, ln1_b, WtBf,
                                          Xb, Q0, K0, Vt0, G0);

  for(int li=0; li<4; li++){
    u16* Wt_l = WtBf + (size_t)li*196608;
    const float* gnw_l = gn_w + (size_t)li*VDIM;
    const float* gnb_l = gn_b + (size_t)li*VDIM;
    const float* l2w = ln2_w + (size_t)li*HID, *l2b = ln2_b + (size_t)li*HID;
    const float* f1b = ffn_b1 + (size_t)li*FFND;
    const float* f2b = ffn_b2 + (size_t)li*HID;
    int nli = (li+1)&3;
    const float* n1w = ln1_w + (size_t)nli*HID, *n1b = ln1_b + (size_t)nli*HID;
    const u16* Wq_next = (li<3) ? (WtBf + (size_t)(li+1)*196608) : nullptr;

    const u16* Qi  = (li&1) ? Q1  : Q0;
    const u16* Ki  = (li&1) ? K1  : K0;
    const u16* Vti = (li&1) ? Vt1 : Vt0;
    const u16* Gi  = (li&1) ? G1  : G0;
    u16* Qo  = (li&1) ? Q0  : Q1;
    u16* Ko  = (li&1) ? K0  : K1;
    u16* Vto = (li&1) ? Vt0 : Vt1;
    u16* Go  = (li&1) ? G0  : G1;

    layer_kernel<<<BT/64, 512, 0, stream>>>(
        Qi, Ki, Vti, Gi, gnw_l, gnb_l, l2g,
        Wt_l+98304, Wt_l+131072, f1b, Wt_l+163840, f2b,
        Xb, l2w, l2b, n1w, n1b, Xb,
        Wq_next, Qo, Ko, Vto, Go,
        WtBf+786432, dec_b1, dec_w2, dec_b2, outp);
  }
}